// Round 10
// baseline (655.511 us; speedup 1.0000x reference)
//
#include <hip/hip_runtime.h>
#include <hip/hip_cooperative_groups.h>
#include <math.h>

namespace cg = cooperative_groups;

#define N_NODES 50000
#define E_EDGES 800000
#define ET      (E_EDGES + N_NODES)   // edges + self loops
#define IN_DIM  128
#define HID     128
#define HEADS   8
#define C1      16
#define OUT_DIM 64
#define NEG_SLOPE 0.2f
#define LOG2E   1.4426950408889634f

#define TILE    8192
#define NT      ((ET + TILE - 1) / TILE)      // 104 tiles
#define NB      ((N_NODES + 255) / 256)       // 196 buckets of 256 nodes

#define CONV_BLOCKS (N_NODES * IN_DIM / 4 / 256)   // 6250
#define PREP_BLOCKS 112
#define MEGA_A (NT + CONV_BLOCKS + PREP_BLOCKS)    // 6466
#define L1T_BLOCKS ((N_NODES + 63) / 64)           // 782
#define MEGA_B (NB + L1T_BLOCKS)                   // 978

typedef unsigned int uint32;
typedef __attribute__((ext_vector_type(8))) short bf16x8;
typedef __attribute__((ext_vector_type(4))) float f32x4;

static __device__ __forceinline__ unsigned short f2bf(float f) {
    uint32 u = __float_as_uint(f);
    u += 0x7FFFu + ((u >> 16) & 1u);   // round to nearest even
    return (unsigned short)(u >> 16);
}

struct MegaParams {
    const int* src; const int* dst;
    const float* x;
    const float* W1; const float* as1; const float* ad1; const float* b1;
    const float* W2; const float* as2; const float* ad2; const float* b2;
    float* out;
    unsigned short* xb; unsigned short* h1b; unsigned short* h_act_b; unsigned short* h2b;
    unsigned short* w1t; unsigned short* p1t; unsigned short* w2t; unsigned short* p2t;
    float* a_src1; float* a_dst1; float* a_src2; float* a_dst2;
    int* row_start; int* csr_src; int2* pairs;
    int* cnt; int* tileOff; int* bucketStart;
};

// One persistent cooperative kernel: 7 phases separated by grid.sync().
// Phase bodies are the round-8 kernels, grid-strided.
__global__ __launch_bounds__(256) void mega(MegaParams P) {
    cg::grid_group grid = cg::this_grid();
    const int t = threadIdx.x;
    const int G = gridDim.x;
    __shared__ int sm1[256];
    __shared__ int sm2[256];

    // ---------- phase 1: bucket hist + x->bf16 + weight prep ----------
    for (int blk = blockIdx.x; blk < MEGA_A; blk += G) {
        if (blk < NT) {
            __syncthreads();                       // sm1 reuse guard
            for (int b = t; b < NB; b += 256) sm1[b] = 0;
            __syncthreads();
            int base = blk * TILE;
            #pragma unroll
            for (int it = 0; it < TILE / 256; ++it) {
                int i = base + it * 256 + t;
                if (i < ET) {
                    int d = (i < E_EDGES) ? P.dst[i] : (i - E_EDGES);
                    atomicAdd(&sm1[d >> 8], 1);
                }
            }
            __syncthreads();
            for (int b = t; b < NB; b += 256) P.cnt[blk * NB + b] = sm1[b];
        } else if (blk < NT + CONV_BLOCKS) {
            int i = (blk - NT) * 256 + t;
            float4 v = ((const float4*)P.x)[i];
            ushort4 o;
            o.x = f2bf(v.x); o.y = f2bf(v.y); o.z = f2bf(v.z); o.w = f2bf(v.w);
            ((ushort4*)P.xb)[i] = o;
        } else {
            int b = blk - NT - CONV_BLOCKS;    // 0..111
            if (b < 64) {
                int i = b * 256 + t;                // n*128+k
                int n = i >> 7, k = i & 127;
                P.w1t[n * IN_DIM + k] = f2bf(P.W1[k * HID + n]);
            } else if (b < 96) {
                int i = (b - 64) * 256 + t;         // n*128+k, n<64
                int n = i >> 7, k = i & 127;
                P.w2t[n * HID + k] = f2bf(P.W2[k * OUT_DIM + n]);
            } else if (b < 104) {
                int i = (b - 96) * 256 + t;         // j*128+k, j<16
                int j = i >> 7, k = i & 127;
                int hh = j & 7;
                const float* a = (j < 8) ? P.as1 : P.ad1;
                float acc = 0.f;
                #pragma unroll
                for (int c = 0; c < C1; ++c)
                    acc = fmaf(P.W1[k * HID + hh * C1 + c], a[hh * C1 + c], acc);
                P.p1t[j * IN_DIM + k] = f2bf(acc * LOG2E);
            } else {
                int i = (b - 104) * 256 + t;        // j*128+k, j<16
                int j = i >> 7, k = i & 127;
                if (j < 2) {
                    const float* a = (j == 0) ? P.as2 : P.ad2;
                    float acc = 0.f;
                    #pragma unroll
                    for (int c = 0; c < OUT_DIM; ++c)
                        acc = fmaf(P.W2[k * OUT_DIM + c], a[c], acc);
                    P.p2t[j * HID + k] = f2bf(acc * LOG2E);
                } else {
                    P.p2t[j * HID + k] = 0;
                }
            }
        }
    }
    grid.sync();

    // ---------- phase 2: bucket scan (block 0 only) ----------
    if (blockIdx.x == 0) {
        int total = 0;
        if (t < NB) {
            int run = 0;
            for (int k = 0; k < NT; ++k) {
                int c = P.cnt[k * NB + t];       // coalesced across t
                P.tileOff[k * NB + t] = run;
                run += c;
            }
            total = run;
        }
        sm1[t] = total;
        __syncthreads();
        #pragma unroll
        for (int off = 1; off < 256; off <<= 1) {
            int add = (t >= off) ? sm1[t - off] : 0;
            __syncthreads();
            sm1[t] += add;
            __syncthreads();
        }
        if (t < NB) P.bucketStart[t] = sm1[t] - total;   // exclusive
        if (t == 0) P.bucketStart[NB] = ET;
    }
    grid.sync();

    // ---------- phase 3: bucket scatter ----------
    for (int tile = blockIdx.x; tile < NT; tile += G) {
        __syncthreads();                       // sm1 reuse guard
        for (int b = t; b < NB; b += 256)
            sm1[b] = P.bucketStart[b] + P.tileOff[tile * NB + b];
        __syncthreads();
        int base = tile * TILE;
        #pragma unroll
        for (int it = 0; it < TILE / 256; ++it) {
            int i = base + it * 256 + t;
            if (i < ET) {
                int s, d;
                if (i < E_EDGES) { s = P.src[i]; d = P.dst[i]; }
                else             { s = d = i - E_EDGES; }
                int pos = atomicAdd(&sm1[d >> 8], 1);
                P.pairs[pos] = make_int2(s, d);
            }
        }
    }
    grid.sync();

    // ---------- phase 4: per-bucket CSR build + layer-1 transform (MFMA) ----------
    for (int u = blockIdx.x; u < MEGA_B; u += G) {
        if (u < NB) {
            __syncthreads();                   // sm1/sm2 reuse guard
            int b = u;
            int beg = P.bucketStart[b], end = P.bucketStart[b + 1];
            sm1[t] = 0;
            __syncthreads();
            for (int j = beg + t; j < end; j += 256)
                atomicAdd(&sm1[P.pairs[j].y & 255], 1);
            __syncthreads();
            int v = sm1[t];
            sm2[t] = v;
            __syncthreads();
            #pragma unroll
            for (int off = 1; off < 256; off <<= 1) {
                int add = (t >= off) ? sm2[t - off] : 0;
                __syncthreads();
                sm2[t] += add;
                __syncthreads();
            }
            int pos0 = beg + sm2[t] - v;   // exclusive prefix within bucket
            int n = b * 256 + t;
            if (n < N_NODES) P.row_start[n] = pos0;
            if (b == 0 && t == 0) P.row_start[N_NODES] = ET;
            __syncthreads();
            sm2[t] = pos0;                 // reuse as cursor
            __syncthreads();
            for (int j = beg + t; j < end; j += 256) {
                int2 p = P.pairs[j];
                int pos = atomicAdd(&sm2[p.y & 255], 1);
                P.csr_src[pos] = p.x;
            }
        } else {
            int bb = u - NB;
            int w = t >> 6, lane = t & 63;
            int l15 = lane & 15, quad = lane >> 4;
            int n0 = bb * 64 + w * 16;
            int mrow = n0 + l15;
            int mload = (mrow < N_NODES) ? mrow : (N_NODES - 1);

            bf16x8 af[4];
            #pragma unroll
            for (int s = 0; s < 4; ++s)
                af[s] = *(const bf16x8*)&P.xb[(size_t)mload * IN_DIM + s * 32 + quad * 8];

            #pragma unroll
            for (int tt = 0; tt < 9; ++tt) {
                const unsigned short* Brow = (tt < 8) ? &P.w1t[(tt * 16 + l15) * IN_DIM]
                                                      : &P.p1t[l15 * IN_DIM];
                f32x4 acc = {0.f, 0.f, 0.f, 0.f};
                #pragma unroll
                for (int s = 0; s < 4; ++s) {
                    bf16x8 bf = *(const bf16x8*)&Brow[s * 32 + quad * 8];
                    acc = __builtin_amdgcn_mfma_f32_16x16x32_bf16(af[s], bf, acc, 0, 0, 0);
                }
                int nodeb = n0 + quad * 4;
                if (tt < 8) {
                    int ch = tt * 16 + l15;
                    #pragma unroll
                    for (int r = 0; r < 4; ++r)
                        if (nodeb + r < N_NODES)
                            P.h1b[(size_t)(nodeb + r) * HID + ch] = f2bf(acc[r]);
                } else {
                    #pragma unroll
                    for (int r = 0; r < 4; ++r) {
                        if (nodeb + r < N_NODES) {
                            if (l15 < 8) P.a_src1[(nodeb + r) * HEADS + l15] = acc[r];
                            else         P.a_dst1[(nodeb + r) * HEADS + (l15 - 8)] = acc[r];
                        }
                    }
                }
            }
        }
    }
    grid.sync();

    // ---------- phase 5: layer-1 aggregate (wave per node, exp2 softmax) ----------
    {
        int w = t >> 6, lane = t & 63;
        int c0 = lane * 2;
        int h = lane >> 3;
        for (int g5 = blockIdx.x; g5 < N_NODES / 4; g5 += G) {
            int n = g5 * 4 + w;
            int beg = P.row_start[n], end = P.row_start[n + 1];
            float adst = P.a_dst1[n * HEADS + h];
            float l = 0.f, accx = 0.f, accy = 0.f;

            auto update = [&](float e, uint32 u) {
                float vx = __uint_as_float(u << 16);
                float vy = __uint_as_float(u & 0xFFFF0000u);
                e += adst;
                e = fmaxf(e, NEG_SLOPE * e);          // leaky relu (log2 domain)
                float p = exp2f(e);                   // a's pre-scaled by log2(e)
                l += p;
                accx = fmaf(p, vx, accx);
                accy = fmaf(p, vy, accy);
            };

            int j = beg;
            for (; j + 8 <= end; j += 8) {
                int ss[8];
                #pragma unroll
                for (int q = 0; q < 8; ++q) ss[q] = P.csr_src[j + q];
                float ee[8]; uint32 uu[8];
                #pragma unroll
                for (int q = 0; q < 8; ++q) ee[q] = P.a_src1[ss[q] * HEADS + h];
                #pragma unroll
                for (int q = 0; q < 8; ++q) uu[q] = *(const uint32*)&P.h1b[(size_t)ss[q] * HID + c0];
                #pragma unroll
                for (int q = 0; q < 8; ++q) update(ee[q], uu[q]);
            }
            for (; j + 4 <= end; j += 4) {
                int ss[4];
                #pragma unroll
                for (int q = 0; q < 4; ++q) ss[q] = P.csr_src[j + q];
                float ee[4]; uint32 uu[4];
                #pragma unroll
                for (int q = 0; q < 4; ++q) ee[q] = P.a_src1[ss[q] * HEADS + h];
                #pragma unroll
                for (int q = 0; q < 4; ++q) uu[q] = *(const uint32*)&P.h1b[(size_t)ss[q] * HID + c0];
                #pragma unroll
                for (int q = 0; q < 4; ++q) update(ee[q], uu[q]);
            }
            for (; j < end; ++j) {
                int s = P.csr_src[j];
                float e = P.a_src1[s * HEADS + h];
                uint32 u = *(const uint32*)&P.h1b[(size_t)s * HID + c0];
                update(e, u);
            }

            float inv = 1.f / (l + 1e-16f);
            float vx = accx * inv + P.b1[c0];
            float vy = accy * inv + P.b1[c0 + 1];
            vx = vx > 0.f ? vx : (__expf(vx) - 1.f);   // ELU
            vy = vy > 0.f ? vy : (__expf(vy) - 1.f);
            uint32 packed = (uint32)f2bf(vx) | ((uint32)f2bf(vy) << 16);
            *(uint32*)&P.h_act_b[(size_t)n * HID + c0] = packed;
        }
    }
    grid.sync();

    // ---------- phase 6: layer-2 transform (MFMA) ----------
    for (int u = blockIdx.x; u < L1T_BLOCKS; u += G) {
        int w = t >> 6, lane = t & 63;
        int l15 = lane & 15, quad = lane >> 4;
        int n0 = u * 64 + w * 16;
        int mrow = n0 + l15;
        int mload = (mrow < N_NODES) ? mrow : (N_NODES - 1);

        bf16x8 af[4];
        #pragma unroll
        for (int s = 0; s < 4; ++s)
            af[s] = *(const bf16x8*)&P.h_act_b[(size_t)mload * HID + s * 32 + quad * 8];

        #pragma unroll
        for (int tt = 0; tt < 5; ++tt) {
            const unsigned short* Brow = (tt < 4) ? &P.w2t[(tt * 16 + l15) * HID]
                                                  : &P.p2t[l15 * HID];
            f32x4 acc = {0.f, 0.f, 0.f, 0.f};
            #pragma unroll
            for (int s = 0; s < 4; ++s) {
                bf16x8 bf = *(const bf16x8*)&Brow[s * 32 + quad * 8];
                acc = __builtin_amdgcn_mfma_f32_16x16x32_bf16(af[s], bf, acc, 0, 0, 0);
            }
            int nodeb = n0 + quad * 4;
            if (tt < 4) {
                int ch = tt * 16 + l15;
                #pragma unroll
                for (int r = 0; r < 4; ++r)
                    if (nodeb + r < N_NODES)
                        P.h2b[(size_t)(nodeb + r) * OUT_DIM + ch] = f2bf(acc[r]);
            } else {
                #pragma unroll
                for (int r = 0; r < 4; ++r) {
                    if (nodeb + r < N_NODES) {
                        if (l15 == 0) P.a_src2[nodeb + r] = acc[r];
                        else if (l15 == 1) P.a_dst2[nodeb + r] = acc[r];
                    }
                }
            }
        }
    }
    grid.sync();

    // ---------- phase 7: layer-2 aggregate + log_softmax ----------
    {
        int w = t >> 6, lane = t & 63;
        for (int g7 = blockIdx.x; g7 < N_NODES / 4; g7 += G) {
            int n = g7 * 4 + w;
            int beg = P.row_start[n], end = P.row_start[n + 1];
            float adst = P.a_dst2[n];
            float l = 0.f, acc = 0.f;

            auto update = [&](float e, unsigned short us) {
                float v = __uint_as_float(((uint32)us) << 16);
                e += adst;
                e = fmaxf(e, NEG_SLOPE * e);
                float p = exp2f(e);
                l += p;
                acc = fmaf(p, v, acc);
            };

            int j = beg;
            for (; j + 8 <= end; j += 8) {
                int ss[8];
                #pragma unroll
                for (int q = 0; q < 8; ++q) ss[q] = P.csr_src[j + q];
                float ee[8]; unsigned short vv[8];
                #pragma unroll
                for (int q = 0; q < 8; ++q) ee[q] = P.a_src2[ss[q]];
                #pragma unroll
                for (int q = 0; q < 8; ++q) vv[q] = P.h2b[(size_t)ss[q] * OUT_DIM + lane];
                #pragma unroll
                for (int q = 0; q < 8; ++q) update(ee[q], vv[q]);
            }
            for (; j + 4 <= end; j += 4) {
                int ss[4];
                #pragma unroll
                for (int q = 0; q < 4; ++q) ss[q] = P.csr_src[j + q];
                float ee[4]; unsigned short vv[4];
                #pragma unroll
                for (int q = 0; q < 4; ++q) ee[q] = P.a_src2[ss[q]];
                #pragma unroll
                for (int q = 0; q < 4; ++q) vv[q] = P.h2b[(size_t)ss[q] * OUT_DIM + lane];
                #pragma unroll
                for (int q = 0; q < 4; ++q) update(ee[q], vv[q]);
            }
            for (; j < end; ++j) {
                int s = P.csr_src[j];
                update(P.a_src2[s], P.h2b[(size_t)s * OUT_DIM + lane]);
            }

            float o = acc / (l + 1e-16f) + P.b2[lane];
            // log_softmax over 64 channels (one wave)
            float mx = o;
            #pragma unroll
            for (int ww = 32; ww > 0; ww >>= 1) mx = fmaxf(mx, __shfl_xor(mx, ww, 64));
            float ex = __expf(o - mx);
            float ssum = ex;
            #pragma unroll
            for (int ww = 32; ww > 0; ww >>= 1) ssum += __shfl_xor(ssum, ww, 64);
            P.out[(size_t)n * OUT_DIM + lane] = o - mx - __logf(ssum);
        }
    }
}

// ---------------- launch ----------------

extern "C" void kernel_launch(void* const* d_in, const int* in_sizes, int n_in,
                              void* d_out, int out_size, void* d_ws, size_t ws_size,
                              hipStream_t stream) {
    const float* x   = (const float*)d_in[0];
    const int*   ei  = (const int*)d_in[1];
    const float* W1  = (const float*)d_in[2];
    const float* as1 = (const float*)d_in[3];
    const float* ad1 = (const float*)d_in[4];
    const float* b1  = (const float*)d_in[5];
    const float* W2  = (const float*)d_in[6];
    const float* as2 = (const float*)d_in[7];
    const float* ad2 = (const float*)d_in[8];
    const float* b2  = (const float*)d_in[9];
    float* out = (float*)d_out;

    char* ws = (char*)d_ws;
    size_t off = 0;
    auto alloc = [&](size_t bytes) -> void* {
        void* p = ws + off;
        off += (bytes + 255) & ~size_t(255);
        return p;
    };
    MegaParams P;
    P.src = ei;             // row 0
    P.dst = ei + E_EDGES;   // row 1
    P.x = x; P.W1 = W1; P.as1 = as1; P.ad1 = ad1; P.b1 = b1;
    P.W2 = W2; P.as2 = as2; P.ad2 = ad2; P.b2 = b2;
    P.out = out;
    P.xb      = (unsigned short*)alloc((size_t)N_NODES * IN_DIM * 2);
    P.h1b     = (unsigned short*)alloc((size_t)N_NODES * HID * 2);
    P.h_act_b = (unsigned short*)alloc((size_t)N_NODES * HID * 2);
    P.h2b     = (unsigned short*)alloc((size_t)N_NODES * OUT_DIM * 2);
    P.w1t     = (unsigned short*)alloc((size_t)HID * IN_DIM * 2);
    P.p1t     = (unsigned short*)alloc((size_t)16 * IN_DIM * 2);
    P.w2t     = (unsigned short*)alloc((size_t)OUT_DIM * HID * 2);
    P.p2t     = (unsigned short*)alloc((size_t)16 * HID * 2);
    P.a_src1  = (float*)alloc((size_t)N_NODES * HEADS * 4);
    P.a_dst1  = (float*)alloc((size_t)N_NODES * HEADS * 4);
    P.a_src2  = (float*)alloc((size_t)N_NODES * 4);
    P.a_dst2  = (float*)alloc((size_t)N_NODES * 4);
    P.row_start = (int*)alloc((size_t)(N_NODES + 1) * 4);
    P.csr_src   = (int*)alloc((size_t)ET * 4);
    P.pairs     = (int2*)alloc((size_t)ET * 8);
    P.cnt       = (int*)alloc((size_t)NB * NT * 4);
    P.tileOff   = (int*)alloc((size_t)NB * NT * 4);
    P.bucketStart = (int*)alloc((size_t)(NB + 1) * 4);

    int perCU = 0;
    hipOccupancyMaxActiveBlocksPerMultiprocessor(&perCU, mega, 256, 0);
    if (perCU < 1) perCU = 1;
    int G = perCU * 256;                 // 256 CUs on MI355X
    if (G > 2048) G = 2048;

    void* args[] = { (void*)&P };
    hipLaunchCooperativeKernel((const void*)mega, dim3(G), dim3(256), args, 0, stream);
}

// Round 11
// 230.449 us; speedup vs baseline: 2.8445x; 2.8445x over previous
//
#include <hip/hip_runtime.h>
#include <math.h>

#define N_NODES 50000
#define E_EDGES 800000
#define ET      (E_EDGES + N_NODES)   // edges + self loops
#define IN_DIM  128
#define HID     128
#define HEADS   8
#define C1      16
#define OUT_DIM 64
#define NEG_SLOPE 0.2f
#define LOG2E   1.4426950408889634f

#define TILE    8192
#define NT      ((ET + TILE - 1) / TILE)      // 104 tiles
#define NB      ((N_NODES + 255) / 256)       // 196 buckets of 256 nodes

#define CONV_BLOCKS (N_NODES * IN_DIM / 4 / 256)   // 6250
#define PREP_BLOCKS 112
#define MEGA_A (NT + CONV_BLOCKS + PREP_BLOCKS)    // 6466
#define L1T_BLOCKS ((N_NODES + 63) / 64)           // 782
#define MEGA_B (NB + L1T_BLOCKS)                   // 978

typedef unsigned int uint32;
typedef __attribute__((ext_vector_type(8))) short bf16x8;
typedef __attribute__((ext_vector_type(4))) float f32x4;

static __device__ __forceinline__ unsigned short f2bf(float f) {
    uint32 u = __float_as_uint(f);
    u += 0x7FFFu + ((u >> 16) & 1u);   // round to nearest even
    return (unsigned short)(u >> 16);
}

// ---------------- Mega-kernel A: bucket_hist + convert_x + prep_weights ----------------
// cnt layout [NT][NB] so prefix recompute reads coalesced across lanes.
// p1t/p2t rows are pre-scaled by log2(e) so aggregates use bare exp2f.

__global__ __launch_bounds__(256) void prep_all(
        const int* __restrict__ dst, int* __restrict__ cnt,
        const float* __restrict__ x, unsigned short* __restrict__ xb,
        const float* __restrict__ W1, const float* __restrict__ as1,
        const float* __restrict__ ad1, const float* __restrict__ W2,
        const float* __restrict__ as2, const float* __restrict__ ad2,
        unsigned short* __restrict__ w1t, unsigned short* __restrict__ p1t,
        unsigned short* __restrict__ w2t, unsigned short* __restrict__ p2t) {
    __shared__ int hist[NB];
    int blk = blockIdx.x, t = threadIdx.x;
    if (blk < NT) {
        for (int b = t; b < NB; b += 256) hist[b] = 0;
        __syncthreads();
        int base = blk * TILE;
        #pragma unroll
        for (int it = 0; it < TILE / 256; ++it) {
            int i = base + it * 256 + t;
            if (i < ET) {
                int d = (i < E_EDGES) ? dst[i] : (i - E_EDGES);
                atomicAdd(&hist[d >> 8], 1);
            }
        }
        __syncthreads();
        for (int b = t; b < NB; b += 256) cnt[blk * NB + b] = hist[b];
    } else if (blk < NT + CONV_BLOCKS) {
        int i = (blk - NT) * 256 + t;
        float4 v = ((const float4*)x)[i];
        ushort4 o;
        o.x = f2bf(v.x); o.y = f2bf(v.y); o.z = f2bf(v.z); o.w = f2bf(v.w);
        ((ushort4*)xb)[i] = o;
    } else {
        int b = blk - NT - CONV_BLOCKS;    // 0..111
        if (b < 64) {
            int i = b * 256 + t;                // n*128+k
            int n = i >> 7, k = i & 127;
            w1t[n * IN_DIM + k] = f2bf(W1[k * HID + n]);
        } else if (b < 96) {
            int i = (b - 64) * 256 + t;         // n*128+k, n<64
            int n = i >> 7, k = i & 127;
            w2t[n * HID + k] = f2bf(W2[k * OUT_DIM + n]);
        } else if (b < 104) {
            int i = (b - 96) * 256 + t;         // j*128+k, j<16
            int j = i >> 7, k = i & 127;
            int hh = j & 7;
            const float* a = (j < 8) ? as1 : ad1;
            float acc = 0.f;
            #pragma unroll
            for (int c = 0; c < C1; ++c)
                acc = fmaf(W1[k * HID + hh * C1 + c], a[hh * C1 + c], acc);
            p1t[j * IN_DIM + k] = f2bf(acc * LOG2E);
        } else {
            int i = (b - 104) * 256 + t;        // j*128+k, j<16
            int j = i >> 7, k = i & 127;
            if (j < 2) {
                const float* a = (j == 0) ? as2 : ad2;
                float acc = 0.f;
                #pragma unroll
                for (int c = 0; c < OUT_DIM; ++c)
                    acc = fmaf(W2[k * OUT_DIM + c], a[c], acc);
                p2t[j * HID + k] = f2bf(acc * LOG2E);
            } else {
                p2t[j * HID + k] = 0;
            }
        }
    }
}

// ---------------- bucket_scatter (scan fused in) ----------------
// Each block recomputes bucket prefixes from cnt (L2-resident, coalesced reads);
// block 0 also publishes bucketStart for build_l1t. Edges packed to uint32:
// (src << 8) | (dst & 255).

__global__ __launch_bounds__(256) void bucket_scatter(
        const int* __restrict__ src, const int* __restrict__ dst,
        const int* __restrict__ cnt, int* __restrict__ bucketStart,
        uint32* __restrict__ pairs) {
    __shared__ int lcur[NB];
    __shared__ int sscan[256];
    int t = threadIdx.x;
    int tile = blockIdx.x;

    int run = 0, total = 0;
    if (t < NB) {
        for (int k = 0; k < NT; ++k) {
            int c = cnt[k * NB + t];     // coalesced across t
            if (k < tile) run += c;
            total += c;
        }
    }
    sscan[t] = (t < NB) ? total : 0;
    __syncthreads();
    #pragma unroll
    for (int off = 1; off < 256; off <<= 1) {
        int add = (t >= off) ? sscan[t - off] : 0;
        __syncthreads();
        sscan[t] += add;
        __syncthreads();
    }
    int bstart = sscan[t] - total;       // exclusive prefix
    if (t < NB) {
        lcur[t] = bstart + run;
        if (tile == 0) bucketStart[t] = bstart;
    }
    if (tile == 0 && t == 0) bucketStart[NB] = ET;
    __syncthreads();

    int base = tile * TILE;
    #pragma unroll
    for (int it = 0; it < TILE / 256; ++it) {
        int i = base + it * 256 + t;
        if (i < ET) {
            int s, d;
            if (i < E_EDGES) { s = src[i]; d = dst[i]; }
            else             { s = d = i - E_EDGES; }
            int pos = atomicAdd(&lcur[d >> 8], 1);
            pairs[pos] = ((uint32)s << 8) | (uint32)(d & 255);
        }
    }
}

// ---------------- Mega-kernel B: bucket_build + l1_transform_mfma ----------------

__global__ __launch_bounds__(256) void build_l1t(
        const uint32* __restrict__ pairs, const int* __restrict__ bucketStart,
        int* __restrict__ row_start, int* __restrict__ csr_src,
        const unsigned short* __restrict__ xb, const unsigned short* __restrict__ w1t,
        const unsigned short* __restrict__ p1t, unsigned short* __restrict__ h1b,
        float* __restrict__ a_src, float* __restrict__ a_dst) {
    __shared__ int sdeg[256];
    __shared__ int sscan[256];
    int t = threadIdx.x;
    if (blockIdx.x < NB) {
        int b = blockIdx.x;
        int beg = bucketStart[b], end = bucketStart[b + 1];
        sdeg[t] = 0;
        __syncthreads();
        for (int j = beg + t; j < end; j += 256)
            atomicAdd(&sdeg[pairs[j] & 255u], 1);
        __syncthreads();
        int v = sdeg[t];
        sscan[t] = v;
        __syncthreads();
        #pragma unroll
        for (int off = 1; off < 256; off <<= 1) {
            int add = (t >= off) ? sscan[t - off] : 0;
            __syncthreads();
            sscan[t] += add;
            __syncthreads();
        }
        int pos0 = beg + sscan[t] - v;   // exclusive prefix within bucket
        int n = b * 256 + t;
        if (n < N_NODES) row_start[n] = pos0;
        if (b == 0 && t == 0) row_start[N_NODES] = ET;
        __syncthreads();
        sscan[t] = pos0;                 // reuse as cursor
        __syncthreads();
        for (int j = beg + t; j < end; j += 256) {
            uint32 p = pairs[j];
            int pos = atomicAdd(&sscan[p & 255u], 1);
            csr_src[pos] = (int)(p >> 8);
        }
        return;
    }
    // ---- layer-1 transform via MFMA, LDS-free ----
    int bb = blockIdx.x - NB;
    int w = t >> 6, lane = t & 63;
    int l15 = lane & 15, quad = lane >> 4;
    int n0 = bb * 64 + w * 16;
    int mrow = n0 + l15;
    int mload = (mrow < N_NODES) ? mrow : (N_NODES - 1);

    bf16x8 af[4];
    #pragma unroll
    for (int s = 0; s < 4; ++s)
        af[s] = *(const bf16x8*)&xb[(size_t)mload * IN_DIM + s * 32 + quad * 8];

    #pragma unroll
    for (int tt = 0; tt < 9; ++tt) {
        const unsigned short* Brow = (tt < 8) ? &w1t[(tt * 16 + l15) * IN_DIM]
                                              : &p1t[l15 * IN_DIM];
        f32x4 acc = {0.f, 0.f, 0.f, 0.f};
        #pragma unroll
        for (int s = 0; s < 4; ++s) {
            bf16x8 bf = *(const bf16x8*)&Brow[s * 32 + quad * 8];
            acc = __builtin_amdgcn_mfma_f32_16x16x32_bf16(af[s], bf, acc, 0, 0, 0);
        }
        int nodeb = n0 + quad * 4;
        if (tt < 8) {
            int ch = tt * 16 + l15;
            #pragma unroll
            for (int r = 0; r < 4; ++r)
                if (nodeb + r < N_NODES)
                    h1b[(size_t)(nodeb + r) * HID + ch] = f2bf(acc[r]);
        } else {
            #pragma unroll
            for (int r = 0; r < 4; ++r) {
                if (nodeb + r < N_NODES) {
                    if (l15 < 8) a_src[(nodeb + r) * HEADS + l15] = acc[r];
                    else         a_dst[(nodeb + r) * HEADS + (l15 - 8)] = acc[r];
                }
            }
        }
    }
}

// ---------------- Layer 1: aggregate (exp2 softmax, unroll x8, uint32 offsets) ----------------

__global__ __launch_bounds__(128) void l1_aggregate(
        const unsigned short* __restrict__ h1b, const float* __restrict__ a_src,
        const float* __restrict__ a_dst, const int* __restrict__ row_start,
        const int* __restrict__ csr_src, const float* __restrict__ b1,
        unsigned short* __restrict__ h_act_b) {
    int w = threadIdx.x >> 6;
    uint32 lane = threadIdx.x & 63;
    int n = blockIdx.x * 2 + w;
    uint32 c0 = lane * 2u;
    uint32 h = lane >> 3;
    int beg = row_start[n], end = row_start[n + 1];
    float adst = a_dst[n * HEADS + h];
    float l = 0.f, accx = 0.f, accy = 0.f;

    auto update = [&](float e, uint32 u) {
        float vx = __uint_as_float(u << 16);
        float vy = __uint_as_float(u & 0xFFFF0000u);
        e += adst;
        e = fmaxf(e, NEG_SLOPE * e);          // leaky relu (log2-scaled domain)
        float p = exp2f(e);                   // a's pre-scaled by log2(e)
        l += p;
        accx = fmaf(p, vx, accx);
        accy = fmaf(p, vy, accy);
    };

    int j = beg;
    for (; j + 8 <= end; j += 8) {
        uint32 ss[8];
        #pragma unroll
        for (int q = 0; q < 8; ++q) ss[q] = (uint32)csr_src[j + q];
        float ee[8]; uint32 uu[8];
        #pragma unroll
        for (int q = 0; q < 8; ++q) ee[q] = a_src[ss[q] * 8u + h];
        #pragma unroll
        for (int q = 0; q < 8; ++q) uu[q] = *(const uint32*)&h1b[(ss[q] << 7) + c0];
        #pragma unroll
        for (int q = 0; q < 8; ++q) update(ee[q], uu[q]);
    }
    for (; j + 4 <= end; j += 4) {
        uint32 ss[4];
        #pragma unroll
        for (int q = 0; q < 4; ++q) ss[q] = (uint32)csr_src[j + q];
        float ee[4]; uint32 uu[4];
        #pragma unroll
        for (int q = 0; q < 4; ++q) ee[q] = a_src[ss[q] * 8u + h];
        #pragma unroll
        for (int q = 0; q < 4; ++q) uu[q] = *(const uint32*)&h1b[(ss[q] << 7) + c0];
        #pragma unroll
        for (int q = 0; q < 4; ++q) update(ee[q], uu[q]);
    }
    for (; j < end; ++j) {
        uint32 s = (uint32)csr_src[j];
        float e = a_src[s * 8u + h];
        uint32 u = *(const uint32*)&h1b[(s << 7) + c0];
        update(e, u);
    }

    float inv = 1.f / (l + 1e-16f);
    float vx = accx * inv + b1[c0];
    float vy = accy * inv + b1[c0 + 1];
    vx = vx > 0.f ? vx : (__expf(vx) - 1.f);   // ELU
    vy = vy > 0.f ? vy : (__expf(vy) - 1.f);
    uint32 packed = (uint32)f2bf(vx) | ((uint32)f2bf(vy) << 16);
    *(uint32*)&h_act_b[(size_t)n * HID + c0] = packed;
}

// ---------------- Layer 2: transform via MFMA, LDS-free ----------------

__global__ __launch_bounds__(256) void l2_transform_mfma(
        const unsigned short* __restrict__ h_act_b, const unsigned short* __restrict__ w2t,
        const unsigned short* __restrict__ p2t, unsigned short* __restrict__ h2b,
        float* __restrict__ a_src2, float* __restrict__ a_dst2) {
    int t = threadIdx.x, w = t >> 6, lane = t & 63;
    int l15 = lane & 15, quad = lane >> 4;
    int n0 = blockIdx.x * 64 + w * 16;
    int mrow = n0 + l15;
    int mload = (mrow < N_NODES) ? mrow : (N_NODES - 1);

    bf16x8 af[4];
    #pragma unroll
    for (int s = 0; s < 4; ++s)
        af[s] = *(const bf16x8*)&h_act_b[(size_t)mload * HID + s * 32 + quad * 8];

    #pragma unroll
    for (int tt = 0; tt < 5; ++tt) {
        const unsigned short* Brow = (tt < 4) ? &w2t[(tt * 16 + l15) * HID]
                                              : &p2t[l15 * HID];
        f32x4 acc = {0.f, 0.f, 0.f, 0.f};
        #pragma unroll
        for (int s = 0; s < 4; ++s) {
            bf16x8 bf = *(const bf16x8*)&Brow[s * 32 + quad * 8];
            acc = __builtin_amdgcn_mfma_f32_16x16x32_bf16(af[s], bf, acc, 0, 0, 0);
        }
        int nodeb = n0 + quad * 4;
        if (tt < 4) {
            int ch = tt * 16 + l15;
            #pragma unroll
            for (int r = 0; r < 4; ++r)
                if (nodeb + r < N_NODES)
                    h2b[(size_t)(nodeb + r) * OUT_DIM + ch] = f2bf(acc[r]);
        } else {
            #pragma unroll
            for (int r = 0; r < 4; ++r) {
                if (nodeb + r < N_NODES) {
                    if (l15 == 0) a_src2[nodeb + r] = acc[r];
                    else if (l15 == 1) a_dst2[nodeb + r] = acc[r];
                }
            }
        }
    }
}

// ---------------- Layer 2: aggregate + log_softmax (unroll x8, uint32 offsets) ----------------

__global__ __launch_bounds__(128) void l2_aggregate(
        const unsigned short* __restrict__ h2b, const float* __restrict__ a_src2,
        const float* __restrict__ a_dst2, const int* __restrict__ row_start,
        const int* __restrict__ csr_src, const float* __restrict__ b2,
        float* __restrict__ out) {
    int w = threadIdx.x >> 6;
    uint32 lane = threadIdx.x & 63;
    int n = blockIdx.x * 2 + w;
    int beg = row_start[n], end = row_start[n + 1];
    float adst = a_dst2[n];
    float l = 0.f, acc = 0.f;

    auto update = [&](float e, unsigned short us) {
        float v = __uint_as_float(((uint32)us) << 16);
        e += adst;
        e = fmaxf(e, NEG_SLOPE * e);
        float p = exp2f(e);                   // a's pre-scaled by log2(e)
        l += p;
        acc = fmaf(p, v, acc);
    };

    int j = beg;
    for (; j + 8 <= end; j += 8) {
        uint32 ss[8];
        #pragma unroll
        for (int q = 0; q < 8; ++q) ss[q] = (uint32)csr_src[j + q];
        float ee[8]; unsigned short vv[8];
        #pragma unroll
        for (int q = 0; q < 8; ++q) ee[q] = a_src2[ss[q]];
        #pragma unroll
        for (int q = 0; q < 8; ++q) vv[q] = h2b[(ss[q] << 6) + lane];
        #pragma unroll
        for (int q = 0; q < 8; ++q) update(ee[q], vv[q]);
    }
    for (; j + 4 <= end; j += 4) {
        uint32 ss[4];
        #pragma unroll
        for (int q = 0; q < 4; ++q) ss[q] = (uint32)csr_src[j + q];
        float ee[4]; unsigned short vv[4];
        #pragma unroll
        for (int q = 0; q < 4; ++q) ee[q] = a_src2[ss[q]];
        #pragma unroll
        for (int q = 0; q < 4; ++q) vv[q] = h2b[(ss[q] << 6) + lane];
        #pragma unroll
        for (int q = 0; q < 4; ++q) update(ee[q], vv[q]);
    }
    for (; j < end; ++j) {
        uint32 s = (uint32)csr_src[j];
        update(a_src2[s], h2b[(s << 6) + lane]);
    }

    float o = acc / (l + 1e-16f) + b2[lane];
    // log_softmax over 64 channels (one wave)
    float mx = o;
    #pragma unroll
    for (int ww = 32; ww > 0; ww >>= 1) mx = fmaxf(mx, __shfl_xor(mx, ww, 64));
    float ex = __expf(o - mx);
    float ssum = ex;
    #pragma unroll
    for (int ww = 32; ww > 0; ww >>= 1) ssum += __shfl_xor(ssum, ww, 64);
    out[(size_t)n * OUT_DIM + lane] = o - mx - __logf(ssum);
}

// ---------------- launch ----------------

extern "C" void kernel_launch(void* const* d_in, const int* in_sizes, int n_in,
                              void* d_out, int out_size, void* d_ws, size_t ws_size,
                              hipStream_t stream) {
    const float* x   = (const float*)d_in[0];
    const int*   ei  = (const int*)d_in[1];
    const float* W1  = (const float*)d_in[2];
    const float* as1 = (const float*)d_in[3];
    const float* ad1 = (const float*)d_in[4];
    const float* b1  = (const float*)d_in[5];
    const float* W2  = (const float*)d_in[6];
    const float* as2 = (const float*)d_in[7];
    const float* ad2 = (const float*)d_in[8];
    const float* b2  = (const float*)d_in[9];
    float* out = (float*)d_out;

    const int* src = ei;             // row 0
    const int* dst = ei + E_EDGES;   // row 1

    char* ws = (char*)d_ws;
    size_t off = 0;
    auto alloc = [&](size_t bytes) -> void* {
        void* p = ws + off;
        off += (bytes + 255) & ~size_t(255);
        return p;
    };
    unsigned short* xb     = (unsigned short*)alloc((size_t)N_NODES * IN_DIM * 2);
    unsigned short* h1b    = (unsigned short*)alloc((size_t)N_NODES * HID * 2);
    unsigned short* h_act_b= (unsigned short*)alloc((size_t)N_NODES * HID * 2);
    unsigned short* h2b    = (unsigned short*)alloc((size_t)N_NODES * OUT_DIM * 2);
    unsigned short* w1t    = (unsigned short*)alloc((size_t)HID * IN_DIM * 2);
    unsigned short* p1t    = (unsigned short*)alloc((size_t)16 * IN_DIM * 2);
    unsigned short* w2t    = (unsigned short*)alloc((size_t)OUT_DIM * HID * 2);
    unsigned short* p2t    = (unsigned short*)alloc((size_t)16 * HID * 2);
    float* a_src1    = (float*)alloc((size_t)N_NODES * HEADS * 4);
    float* a_dst1    = (float*)alloc((size_t)N_NODES * HEADS * 4);
    float* a_src2    = (float*)alloc((size_t)N_NODES * 4);
    float* a_dst2    = (float*)alloc((size_t)N_NODES * 4);
    int*   row_start = (int*)alloc((size_t)(N_NODES + 1) * 4);
    int*   csr_src   = (int*)alloc((size_t)ET * 4);
    uint32* pairs    = (uint32*)alloc((size_t)ET * 4);
    int*   cnt       = (int*)alloc((size_t)NB * NT * 4);
    int*   bucketStart = (int*)alloc((size_t)(NB + 1) * 4);

    prep_all<<<MEGA_A, 256, 0, stream>>>(dst, cnt, x, xb, W1, as1, ad1,
                                         W2, as2, ad2, w1t, p1t, w2t, p2t);
    bucket_scatter<<<NT, 256, 0, stream>>>(src, dst, cnt, bucketStart, pairs);
    build_l1t<<<MEGA_B, 256, 0, stream>>>(pairs, bucketStart, row_start, csr_src,
                                          xb, w1t, p1t, h1b, a_src1, a_dst1);
    l1_aggregate<<<N_NODES / 2, 128, 0, stream>>>(h1b, a_src1, a_dst1, row_start, csr_src, b1, h_act_b);
    l2_transform_mfma<<<L1T_BLOCKS, 256, 0, stream>>>(h_act_b, w2t, p2t, h2b, a_src2, a_dst2);
    l2_aggregate<<<N_NODES / 2, 128, 0, stream>>>(h2b, a_src2, a_dst2, row_start, csr_src, b2, out);
}

// Round 12
// 223.819 us; speedup vs baseline: 2.9288x; 1.0296x over previous
//
#include <hip/hip_runtime.h>
#include <math.h>

#define N_NODES 50000
#define E_EDGES 800000
#define ET      (E_EDGES + N_NODES)   // edges + self loops
#define IN_DIM  128
#define HID     128
#define HEADS   8
#define C1      16
#define OUT_DIM 64
#define NEG_SLOPE 0.2f
#define LOG2E   1.4426950408889634f

#define TILE    8192
#define NT      ((ET + TILE - 1) / TILE)      // 104 tiles
#define NB      ((N_NODES + 255) / 256)       // 196 buckets of 256 nodes

#define CONV_BLOCKS (N_NODES * IN_DIM / 4 / 256)   // 6250
#define PREP_BLOCKS 112
#define MEGA_A (NT + CONV_BLOCKS + PREP_BLOCKS)    // 6466
#define L1T_BLOCKS ((N_NODES + 63) / 64)           // 782
#define MEGA_B (NB + L1T_BLOCKS)                   // 978

typedef unsigned int uint32;
typedef __attribute__((ext_vector_type(8))) short bf16x8;
typedef __attribute__((ext_vector_type(4))) float f32x4;

static __device__ __forceinline__ unsigned short f2bf(float f) {
    uint32 u = __float_as_uint(f);
    u += 0x7FFFu + ((u >> 16) & 1u);   // round to nearest even
    return (unsigned short)(u >> 16);
}

// ---------------- Mega-kernel A: bucket_hist + convert_x + prep_weights ----------------
// cnt layout [NT][NB] so prefix recompute reads coalesced across lanes.
// p1t/p2t rows are pre-scaled by log2(e) so aggregates use bare exp2f.

__global__ __launch_bounds__(256) void prep_all(
        const int* __restrict__ dst, int* __restrict__ cnt,
        const float* __restrict__ x, unsigned short* __restrict__ xb,
        const float* __restrict__ W1, const float* __restrict__ as1,
        const float* __restrict__ ad1, const float* __restrict__ W2,
        const float* __restrict__ as2, const float* __restrict__ ad2,
        unsigned short* __restrict__ w1t, unsigned short* __restrict__ p1t,
        unsigned short* __restrict__ w2t, unsigned short* __restrict__ p2t) {
    __shared__ int hist[NB];
    int blk = blockIdx.x, t = threadIdx.x;
    if (blk < NT) {
        for (int b = t; b < NB; b += 256) hist[b] = 0;
        __syncthreads();
        int base = blk * TILE;
        #pragma unroll
        for (int it = 0; it < TILE / 256; ++it) {
            int i = base + it * 256 + t;
            if (i < ET) {
                int d = (i < E_EDGES) ? dst[i] : (i - E_EDGES);
                atomicAdd(&hist[d >> 8], 1);
            }
        }
        __syncthreads();
        for (int b = t; b < NB; b += 256) cnt[blk * NB + b] = hist[b];
    } else if (blk < NT + CONV_BLOCKS) {
        int i = (blk - NT) * 256 + t;
        float4 v = ((const float4*)x)[i];
        ushort4 o;
        o.x = f2bf(v.x); o.y = f2bf(v.y); o.z = f2bf(v.z); o.w = f2bf(v.w);
        ((ushort4*)xb)[i] = o;
    } else {
        int b = blk - NT - CONV_BLOCKS;    // 0..111
        if (b < 64) {
            int i = b * 256 + t;                // n*128+k
            int n = i >> 7, k = i & 127;
            w1t[n * IN_DIM + k] = f2bf(W1[k * HID + n]);
        } else if (b < 96) {
            int i = (b - 64) * 256 + t;         // n*128+k, n<64
            int n = i >> 7, k = i & 127;
            w2t[n * HID + k] = f2bf(W2[k * OUT_DIM + n]);
        } else if (b < 104) {
            int i = (b - 96) * 256 + t;         // j*128+k, j<16
            int j = i >> 7, k = i & 127;
            int hh = j & 7;
            const float* a = (j < 8) ? as1 : ad1;
            float acc = 0.f;
            #pragma unroll
            for (int c = 0; c < C1; ++c)
                acc = fmaf(W1[k * HID + hh * C1 + c], a[hh * C1 + c], acc);
            p1t[j * IN_DIM + k] = f2bf(acc * LOG2E);
        } else {
            int i = (b - 104) * 256 + t;        // j*128+k, j<16
            int j = i >> 7, k = i & 127;
            if (j < 2) {
                const float* a = (j == 0) ? as2 : ad2;
                float acc = 0.f;
                #pragma unroll
                for (int c = 0; c < OUT_DIM; ++c)
                    acc = fmaf(W2[k * OUT_DIM + c], a[c], acc);
                p2t[j * HID + k] = f2bf(acc * LOG2E);
            } else {
                p2t[j * HID + k] = 0;
            }
        }
    }
}

// ---------------- bucket_scatter (scan fused in) ----------------

__global__ __launch_bounds__(256) void bucket_scatter(
        const int* __restrict__ src, const int* __restrict__ dst,
        const int* __restrict__ cnt, int* __restrict__ bucketStart,
        uint32* __restrict__ pairs) {
    __shared__ int lcur[NB];
    __shared__ int sscan[256];
    int t = threadIdx.x;
    int tile = blockIdx.x;

    int run = 0, total = 0;
    if (t < NB) {
        for (int k = 0; k < NT; ++k) {
            int c = cnt[k * NB + t];     // coalesced across t
            if (k < tile) run += c;
            total += c;
        }
    }
    sscan[t] = (t < NB) ? total : 0;
    __syncthreads();
    #pragma unroll
    for (int off = 1; off < 256; off <<= 1) {
        int add = (t >= off) ? sscan[t - off] : 0;
        __syncthreads();
        sscan[t] += add;
        __syncthreads();
    }
    int bstart = sscan[t] - total;       // exclusive prefix
    if (t < NB) {
        lcur[t] = bstart + run;
        if (tile == 0) bucketStart[t] = bstart;
    }
    if (tile == 0 && t == 0) bucketStart[NB] = ET;
    __syncthreads();

    int base = tile * TILE;
    #pragma unroll
    for (int it = 0; it < TILE / 256; ++it) {
        int i = base + it * 256 + t;
        if (i < ET) {
            int s, d;
            if (i < E_EDGES) { s = src[i]; d = dst[i]; }
            else             { s = d = i - E_EDGES; }
            int pos = atomicAdd(&lcur[d >> 8], 1);
            pairs[pos] = ((uint32)s << 8) | (uint32)(d & 255);
        }
    }
}

// ---------------- Mega-kernel B: bucket_build + l1_transform_mfma ----------------

__global__ __launch_bounds__(256) void build_l1t(
        const uint32* __restrict__ pairs, const int* __restrict__ bucketStart,
        int* __restrict__ row_start, int* __restrict__ csr_src,
        const unsigned short* __restrict__ xb, const unsigned short* __restrict__ w1t,
        const unsigned short* __restrict__ p1t, unsigned short* __restrict__ h1b,
        float* __restrict__ a_src, float* __restrict__ a_dst) {
    __shared__ int sdeg[256];
    __shared__ int sscan[256];
    int t = threadIdx.x;
    if (blockIdx.x < NB) {
        int b = blockIdx.x;
        int beg = bucketStart[b], end = bucketStart[b + 1];
        sdeg[t] = 0;
        __syncthreads();
        for (int j = beg + t; j < end; j += 256)
            atomicAdd(&sdeg[pairs[j] & 255u], 1);
        __syncthreads();
        int v = sdeg[t];
        sscan[t] = v;
        __syncthreads();
        #pragma unroll
        for (int off = 1; off < 256; off <<= 1) {
            int add = (t >= off) ? sscan[t - off] : 0;
            __syncthreads();
            sscan[t] += add;
            __syncthreads();
        }
        int pos0 = beg + sscan[t] - v;   // exclusive prefix within bucket
        int n = b * 256 + t;
        if (n < N_NODES) row_start[n] = pos0;
        if (b == 0 && t == 0) row_start[N_NODES] = ET;
        __syncthreads();
        sscan[t] = pos0;                 // reuse as cursor
        __syncthreads();
        for (int j = beg + t; j < end; j += 256) {
            uint32 p = pairs[j];
            int pos = atomicAdd(&sscan[p & 255u], 1);
            csr_src[pos] = (int)(p >> 8);
        }
        return;
    }
    // ---- layer-1 transform via MFMA, LDS-free ----
    int bb = blockIdx.x - NB;
    int w = t >> 6, lane = t & 63;
    int l15 = lane & 15, quad = lane >> 4;
    int n0 = bb * 64 + w * 16;
    int mrow = n0 + l15;
    int mload = (mrow < N_NODES) ? mrow : (N_NODES - 1);

    bf16x8 af[4];
    #pragma unroll
    for (int s = 0; s < 4; ++s)
        af[s] = *(const bf16x8*)&xb[(size_t)mload * IN_DIM + s * 32 + quad * 8];

    #pragma unroll
    for (int tt = 0; tt < 9; ++tt) {
        const unsigned short* Brow = (tt < 8) ? &w1t[(tt * 16 + l15) * IN_DIM]
                                              : &p1t[l15 * IN_DIM];
        f32x4 acc = {0.f, 0.f, 0.f, 0.f};
        #pragma unroll
        for (int s = 0; s < 4; ++s) {
            bf16x8 bf = *(const bf16x8*)&Brow[s * 32 + quad * 8];
            acc = __builtin_amdgcn_mfma_f32_16x16x32_bf16(af[s], bf, acc, 0, 0, 0);
        }
        int nodeb = n0 + quad * 4;
        if (tt < 8) {
            int ch = tt * 16 + l15;
            #pragma unroll
            for (int r = 0; r < 4; ++r)
                if (nodeb + r < N_NODES)
                    h1b[(size_t)(nodeb + r) * HID + ch] = f2bf(acc[r]);
        } else {
            #pragma unroll
            for (int r = 0; r < 4; ++r) {
                if (nodeb + r < N_NODES) {
                    if (l15 < 8) a_src[(nodeb + r) * HEADS + l15] = acc[r];
                    else         a_dst[(nodeb + r) * HEADS + (l15 - 8)] = acc[r];
                }
            }
        }
    }
}

// ---------------- Layer 1: aggregate (exp2 softmax, unroll x8, uint32 offsets) ----------------

__global__ __launch_bounds__(128) void l1_aggregate(
        const unsigned short* __restrict__ h1b, const float* __restrict__ a_src,
        const float* __restrict__ a_dst, const int* __restrict__ row_start,
        const int* __restrict__ csr_src, const float* __restrict__ b1,
        unsigned short* __restrict__ h_act_b) {
    int w = threadIdx.x >> 6;
    uint32 lane = threadIdx.x & 63;
    int n = blockIdx.x * 2 + w;
    uint32 c0 = lane * 2u;
    uint32 h = lane >> 3;
    int beg = row_start[n], end = row_start[n + 1];
    float adst = a_dst[n * HEADS + h];
    float l = 0.f, accx = 0.f, accy = 0.f;

    auto update = [&](float e, uint32 u) {
        float vx = __uint_as_float(u << 16);
        float vy = __uint_as_float(u & 0xFFFF0000u);
        e += adst;
        e = fmaxf(e, NEG_SLOPE * e);          // leaky relu (log2-scaled domain)
        float p = exp2f(e);                   // a's pre-scaled by log2(e)
        l += p;
        accx = fmaf(p, vx, accx);
        accy = fmaf(p, vy, accy);
    };

    int j = beg;
    for (; j + 8 <= end; j += 8) {
        uint32 ss[8];
        #pragma unroll
        for (int q = 0; q < 8; ++q) ss[q] = (uint32)csr_src[j + q];
        float ee[8]; uint32 uu[8];
        #pragma unroll
        for (int q = 0; q < 8; ++q) ee[q] = a_src[ss[q] * 8u + h];
        #pragma unroll
        for (int q = 0; q < 8; ++q) uu[q] = *(const uint32*)&h1b[(ss[q] << 7) + c0];
        #pragma unroll
        for (int q = 0; q < 8; ++q) update(ee[q], uu[q]);
    }
    for (; j + 4 <= end; j += 4) {
        uint32 ss[4];
        #pragma unroll
        for (int q = 0; q < 4; ++q) ss[q] = (uint32)csr_src[j + q];
        float ee[4]; uint32 uu[4];
        #pragma unroll
        for (int q = 0; q < 4; ++q) ee[q] = a_src[ss[q] * 8u + h];
        #pragma unroll
        for (int q = 0; q < 4; ++q) uu[q] = *(const uint32*)&h1b[(ss[q] << 7) + c0];
        #pragma unroll
        for (int q = 0; q < 4; ++q) update(ee[q], uu[q]);
    }
    for (; j < end; ++j) {
        uint32 s = (uint32)csr_src[j];
        float e = a_src[s * 8u + h];
        uint32 u = *(const uint32*)&h1b[(s << 7) + c0];
        update(e, u);
    }

    float inv = 1.f / (l + 1e-16f);
    float vx = accx * inv + b1[c0];
    float vy = accy * inv + b1[c0 + 1];
    vx = vx > 0.f ? vx : (__expf(vx) - 1.f);   // ELU
    vy = vy > 0.f ? vy : (__expf(vy) - 1.f);
    uint32 packed = (uint32)f2bf(vx) | ((uint32)f2bf(vy) << 16);
    *(uint32*)&h_act_b[(size_t)n * HID + c0] = packed;
}

// ---------------- Layer 2: transform via MFMA, LDS-free ----------------

__global__ __launch_bounds__(256) void l2_transform_mfma(
        const unsigned short* __restrict__ h_act_b, const unsigned short* __restrict__ w2t,
        const unsigned short* __restrict__ p2t, unsigned short* __restrict__ h2b,
        float* __restrict__ a_src2, float* __restrict__ a_dst2) {
    int t = threadIdx.x, w = t >> 6, lane = t & 63;
    int l15 = lane & 15, quad = lane >> 4;
    int n0 = blockIdx.x * 64 + w * 16;
    int mrow = n0 + l15;
    int mload = (mrow < N_NODES) ? mrow : (N_NODES - 1);

    bf16x8 af[4];
    #pragma unroll
    for (int s = 0; s < 4; ++s)
        af[s] = *(const bf16x8*)&h_act_b[(size_t)mload * HID + s * 32 + quad * 8];

    #pragma unroll
    for (int tt = 0; tt < 5; ++tt) {
        const unsigned short* Brow = (tt < 4) ? &w2t[(tt * 16 + l15) * HID]
                                              : &p2t[l15 * HID];
        f32x4 acc = {0.f, 0.f, 0.f, 0.f};
        #pragma unroll
        for (int s = 0; s < 4; ++s) {
            bf16x8 bf = *(const bf16x8*)&Brow[s * 32 + quad * 8];
            acc = __builtin_amdgcn_mfma_f32_16x16x32_bf16(af[s], bf, acc, 0, 0, 0);
        }
        int nodeb = n0 + quad * 4;
        if (tt < 4) {
            int ch = tt * 16 + l15;
            #pragma unroll
            for (int r = 0; r < 4; ++r)
                if (nodeb + r < N_NODES)
                    h2b[(size_t)(nodeb + r) * OUT_DIM + ch] = f2bf(acc[r]);
        } else {
            #pragma unroll
            for (int r = 0; r < 4; ++r) {
                if (nodeb + r < N_NODES) {
                    if (l15 == 0) a_src2[nodeb + r] = acc[r];
                    else if (l15 == 1) a_dst2[nodeb + r] = acc[r];
                }
            }
        }
    }
}

// ---------------- Layer 2: aggregate + log_softmax ----------------
// 2 nodes per wave: lanes 0-31 node A, lanes 32-63 node B; 2 channels/lane
// (dword gathers). Exhausted lanes contribute p = exp2(-1e4) = 0.

__global__ __launch_bounds__(128) void l2_aggregate(
        const unsigned short* __restrict__ h2b, const float* __restrict__ a_src2,
        const float* __restrict__ a_dst2, const int* __restrict__ row_start,
        const int* __restrict__ csr_src, const float* __restrict__ b2,
        float* __restrict__ out) {
    int t = threadIdx.x;
    int w = t >> 6;
    uint32 lane = t & 63;
    uint32 half = lane >> 5;
    uint32 lane32 = lane & 31;
    int n = blockIdx.x * 4 + w * 2 + (int)half;
    uint32 c0 = lane32 * 2u;
    int beg = row_start[n], end = row_start[n + 1];
    int cnt = end - beg;
    int kmax = cnt;
    #pragma unroll
    for (int m = 32; m > 0; m >>= 1) kmax = max(kmax, __shfl_xor(kmax, m, 64));
    float adst = a_dst2[n];
    float l = 0.f, accx = 0.f, accy = 0.f;
    const uint32* h2w = (const uint32*)h2b;

    for (int k = 0; k < kmax; k += 4) {
        uint32 ss[4]; float ee[4]; uint32 uu[4];
        #pragma unroll
        for (int q = 0; q < 4; ++q) {
            int j = beg + k + q;
            int jc = (j < end) ? j : (end - 1);
            ss[q] = (uint32)csr_src[jc];
        }
        #pragma unroll
        for (int q = 0; q < 4; ++q) ee[q] = a_src2[ss[q]];
        #pragma unroll
        for (int q = 0; q < 4; ++q) uu[q] = h2w[(ss[q] << 5) + lane32];
        #pragma unroll
        for (int q = 0; q < 4; ++q) {
            float e = ee[q] + adst;
            e = fmaxf(e, NEG_SLOPE * e);
            e = (k + q < cnt) ? e : -10000.f;   // masked lane -> p = 0
            float p = exp2f(e);
            l += p;
            float vx = __uint_as_float(uu[q] << 16);
            float vy = __uint_as_float(uu[q] & 0xFFFF0000u);
            accx = fmaf(p, vx, accx);
            accy = fmaf(p, vy, accy);
        }
    }

    float inv = 1.f / (l + 1e-16f);
    float ox = accx * inv + b2[c0];
    float oy = accy * inv + b2[c0 + 1];
    // log_softmax over 64 channels = 32 lanes x 2 (half-wave reduction)
    float mx = fmaxf(ox, oy);
    #pragma unroll
    for (int m = 16; m > 0; m >>= 1) mx = fmaxf(mx, __shfl_xor(mx, m, 32));
    float ex = __expf(ox - mx) + __expf(oy - mx);
    #pragma unroll
    for (int m = 16; m > 0; m >>= 1) ex += __shfl_xor(ex, m, 32);
    float lse = mx + __logf(ex);
    float2 o = make_float2(ox - lse, oy - lse);
    *(float2*)&out[(size_t)n * OUT_DIM + c0] = o;
}

// ---------------- launch ----------------

extern "C" void kernel_launch(void* const* d_in, const int* in_sizes, int n_in,
                              void* d_out, int out_size, void* d_ws, size_t ws_size,
                              hipStream_t stream) {
    const float* x   = (const float*)d_in[0];
    const int*   ei  = (const int*)d_in[1];
    const float* W1  = (const float*)d_in[2];
    const float* as1 = (const float*)d_in[3];
    const float* ad1 = (const float*)d_in[4];
    const float* b1  = (const float*)d_in[5];
    const float* W2  = (const float*)d_in[6];
    const float* as2 = (const float*)d_in[7];
    const float* ad2 = (const float*)d_in[8];
    const float* b2  = (const float*)d_in[9];
    float* out = (float*)d_out;

    const int* src = ei;             // row 0
    const int* dst = ei + E_EDGES;   // row 1

    char* ws = (char*)d_ws;
    size_t off = 0;
    auto alloc = [&](size_t bytes) -> void* {
        void* p = ws + off;
        off += (bytes + 255) & ~size_t(255);
        return p;
    };
    unsigned short* xb     = (unsigned short*)alloc((size_t)N_NODES * IN_DIM * 2);
    unsigned short* h1b    = (unsigned short*)alloc((size_t)N_NODES * HID * 2);
    unsigned short* h_act_b= (unsigned short*)alloc((size_t)N_NODES * HID * 2);
    unsigned short* h2b    = (unsigned short*)alloc((size_t)N_NODES * OUT_DIM * 2);
    unsigned short* w1t    = (unsigned short*)alloc((size_t)HID * IN_DIM * 2);
    unsigned short* p1t    = (unsigned short*)alloc((size_t)16 * IN_DIM * 2);
    unsigned short* w2t    = (unsigned short*)alloc((size_t)OUT_DIM * HID * 2);
    unsigned short* p2t    = (unsigned short*)alloc((size_t)16 * HID * 2);
    float* a_src1    = (float*)alloc((size_t)N_NODES * HEADS * 4);
    float* a_dst1    = (float*)alloc((size_t)N_NODES * HEADS * 4);
    float* a_src2    = (float*)alloc((size_t)N_NODES * 4);
    float* a_dst2    = (float*)alloc((size_t)N_NODES * 4);
    int*   row_start = (int*)alloc((size_t)(N_NODES + 1) * 4);
    int*   csr_src   = (int*)alloc((size_t)ET * 4);
    uint32* pairs    = (uint32*)alloc((size_t)ET * 4);
    int*   cnt       = (int*)alloc((size_t)NB * NT * 4);
    int*   bucketStart = (int*)alloc((size_t)(NB + 1) * 4);

    prep_all<<<MEGA_A, 256, 0, stream>>>(dst, cnt, x, xb, W1, as1, ad1,
                                         W2, as2, ad2, w1t, p1t, w2t, p2t);
    bucket_scatter<<<NT, 256, 0, stream>>>(src, dst, cnt, bucketStart, pairs);
    build_l1t<<<MEGA_B, 256, 0, stream>>>(pairs, bucketStart, row_start, csr_src,
                                          xb, w1t, p1t, h1b, a_src1, a_dst1);
    l1_aggregate<<<N_NODES / 2, 128, 0, stream>>>(h1b, a_src1, a_dst1, row_start, csr_src, b1, h_act_b);
    l2_transform_mfma<<<L1T_BLOCKS, 256, 0, stream>>>(h_act_b, w2t, p2t, h2b, a_src2, a_dst2);
    l2_aggregate<<<N_NODES / 4, 128, 0, stream>>>(h2b, a_src2, a_dst2, row_start, csr_src, b2, out);
}

// Round 13
// 221.956 us; speedup vs baseline: 2.9533x; 1.0084x over previous
//
#include <hip/hip_runtime.h>
#include <math.h>

#define N_NODES 50000
#define E_EDGES 800000
#define ET      (E_EDGES + N_NODES)   // edges + self loops
#define IN_DIM  128
#define HID     128
#define HEADS   8
#define C1      16
#define OUT_DIM 64
#define NEG_SLOPE 0.2f
#define LOG2E   1.4426950408889634f

#define TILE    8192
#define NT      ((ET + TILE - 1) / TILE)      // 104 tiles
#define NB      ((N_NODES + 255) / 256)       // 196 buckets of 256 nodes

#define CONV_BLOCKS (N_NODES * IN_DIM / 4 / 256)   // 6250
#define PREP_BLOCKS 112
#define MEGA_A (NT + CONV_BLOCKS + PREP_BLOCKS)    // 6466
#define L1T_BLOCKS ((N_NODES + 63) / 64)           // 782
#define MEGA_B (NB + L1T_BLOCKS)                   // 978

typedef unsigned int uint32;
typedef __attribute__((ext_vector_type(8))) short bf16x8;
typedef __attribute__((ext_vector_type(4))) float f32x4;

static __device__ __forceinline__ unsigned short f2bf(float f) {
    uint32 u = __float_as_uint(f);
    u += 0x7FFFu + ((u >> 16) & 1u);   // round to nearest even
    return (unsigned short)(u >> 16);
}

// ---------------- Mega-kernel A: bucket_hist + convert_x + prep_weights ----------------
// cnt layout [NT][NB] so prefix recompute reads coalesced across lanes.
// p1t/p2t rows are pre-scaled by log2(e) so aggregates use bare exp2f.

__global__ __launch_bounds__(256) void prep_all(
        const int* __restrict__ dst, int* __restrict__ cnt,
        const float* __restrict__ x, unsigned short* __restrict__ xb,
        const float* __restrict__ W1, const float* __restrict__ as1,
        const float* __restrict__ ad1, const float* __restrict__ W2,
        const float* __restrict__ as2, const float* __restrict__ ad2,
        unsigned short* __restrict__ w1t, unsigned short* __restrict__ p1t,
        unsigned short* __restrict__ w2t, unsigned short* __restrict__ p2t) {
    __shared__ int hist[NB];
    int blk = blockIdx.x, t = threadIdx.x;
    if (blk < NT) {
        for (int b = t; b < NB; b += 256) hist[b] = 0;
        __syncthreads();
        int base = blk * TILE;
        #pragma unroll
        for (int it = 0; it < TILE / 256; ++it) {
            int i = base + it * 256 + t;
            if (i < ET) {
                int d = (i < E_EDGES) ? dst[i] : (i - E_EDGES);
                atomicAdd(&hist[d >> 8], 1);
            }
        }
        __syncthreads();
        for (int b = t; b < NB; b += 256) cnt[blk * NB + b] = hist[b];
    } else if (blk < NT + CONV_BLOCKS) {
        int i = (blk - NT) * 256 + t;
        float4 v = ((const float4*)x)[i];
        ushort4 o;
        o.x = f2bf(v.x); o.y = f2bf(v.y); o.z = f2bf(v.z); o.w = f2bf(v.w);
        ((ushort4*)xb)[i] = o;
    } else {
        int b = blk - NT - CONV_BLOCKS;    // 0..111
        if (b < 64) {
            int i = b * 256 + t;                // n*128+k
            int n = i >> 7, k = i & 127;
            w1t[n * IN_DIM + k] = f2bf(W1[k * HID + n]);
        } else if (b < 96) {
            int i = (b - 64) * 256 + t;         // n*128+k, n<64
            int n = i >> 7, k = i & 127;
            w2t[n * HID + k] = f2bf(W2[k * OUT_DIM + n]);
        } else if (b < 104) {
            int i = (b - 96) * 256 + t;         // j*128+k, j<16
            int j = i >> 7, k = i & 127;
            int hh = j & 7;
            const float* a = (j < 8) ? as1 : ad1;
            float acc = 0.f;
            #pragma unroll
            for (int c = 0; c < C1; ++c)
                acc = fmaf(W1[k * HID + hh * C1 + c], a[hh * C1 + c], acc);
            p1t[j * IN_DIM + k] = f2bf(acc * LOG2E);
        } else {
            int i = (b - 104) * 256 + t;        // j*128+k, j<16
            int j = i >> 7, k = i & 127;
            if (j < 2) {
                const float* a = (j == 0) ? as2 : ad2;
                float acc = 0.f;
                #pragma unroll
                for (int c = 0; c < OUT_DIM; ++c)
                    acc = fmaf(W2[k * OUT_DIM + c], a[c], acc);
                p2t[j * HID + k] = f2bf(acc * LOG2E);
            } else {
                p2t[j * HID + k] = 0;
            }
        }
    }
}

// ---------------- bucket_scatter (scan fused in) ----------------

__global__ __launch_bounds__(256) void bucket_scatter(
        const int* __restrict__ src, const int* __restrict__ dst,
        const int* __restrict__ cnt, int* __restrict__ bucketStart,
        uint32* __restrict__ pairs) {
    __shared__ int lcur[NB];
    __shared__ int sscan[256];
    int t = threadIdx.x;
    int tile = blockIdx.x;

    int run = 0, total = 0;
    if (t < NB) {
        for (int k = 0; k < NT; ++k) {
            int c = cnt[k * NB + t];     // coalesced across t
            if (k < tile) run += c;
            total += c;
        }
    }
    sscan[t] = (t < NB) ? total : 0;
    __syncthreads();
    #pragma unroll
    for (int off = 1; off < 256; off <<= 1) {
        int add = (t >= off) ? sscan[t - off] : 0;
        __syncthreads();
        sscan[t] += add;
        __syncthreads();
    }
    int bstart = sscan[t] - total;       // exclusive prefix
    if (t < NB) {
        lcur[t] = bstart + run;
        if (tile == 0) bucketStart[t] = bstart;
    }
    if (tile == 0 && t == 0) bucketStart[NB] = ET;
    __syncthreads();

    int base = tile * TILE;
    #pragma unroll
    for (int it = 0; it < TILE / 256; ++it) {
        int i = base + it * 256 + t;
        if (i < ET) {
            int s, d;
            if (i < E_EDGES) { s = src[i]; d = dst[i]; }
            else             { s = d = i - E_EDGES; }
            int pos = atomicAdd(&lcur[d >> 8], 1);
            pairs[pos] = ((uint32)s << 8) | (uint32)(d & 255);
        }
    }
}

// ---------------- Mega-kernel B: bucket_build + l1_transform_mfma ----------------

__global__ __launch_bounds__(256) void build_l1t(
        const uint32* __restrict__ pairs, const int* __restrict__ bucketStart,
        int* __restrict__ row_start, int* __restrict__ csr_src,
        const unsigned short* __restrict__ xb, const unsigned short* __restrict__ w1t,
        const unsigned short* __restrict__ p1t, unsigned short* __restrict__ h1b,
        float* __restrict__ a_src, float* __restrict__ a_dst) {
    __shared__ int sdeg[256];
    __shared__ int sscan[256];
    int t = threadIdx.x;
    if (blockIdx.x < NB) {
        int b = blockIdx.x;
        int beg = bucketStart[b], end = bucketStart[b + 1];
        sdeg[t] = 0;
        __syncthreads();
        for (int j = beg + t; j < end; j += 256)
            atomicAdd(&sdeg[pairs[j] & 255u], 1);
        __syncthreads();
        int v = sdeg[t];
        sscan[t] = v;
        __syncthreads();
        #pragma unroll
        for (int off = 1; off < 256; off <<= 1) {
            int add = (t >= off) ? sscan[t - off] : 0;
            __syncthreads();
            sscan[t] += add;
            __syncthreads();
        }
        int pos0 = beg + sscan[t] - v;   // exclusive prefix within bucket
        int n = b * 256 + t;
        if (n < N_NODES) row_start[n] = pos0;
        if (b == 0 && t == 0) row_start[N_NODES] = ET;
        __syncthreads();
        sscan[t] = pos0;                 // reuse as cursor
        __syncthreads();
        for (int j = beg + t; j < end; j += 256) {
            uint32 p = pairs[j];
            int pos = atomicAdd(&sscan[p & 255u], 1);
            csr_src[pos] = (int)(p >> 8);
        }
        return;
    }
    // ---- layer-1 transform via MFMA, LDS-free ----
    int bb = blockIdx.x - NB;
    int w = t >> 6, lane = t & 63;
    int l15 = lane & 15, quad = lane >> 4;
    int n0 = bb * 64 + w * 16;
    int mrow = n0 + l15;
    int mload = (mrow < N_NODES) ? mrow : (N_NODES - 1);

    bf16x8 af[4];
    #pragma unroll
    for (int s = 0; s < 4; ++s)
        af[s] = *(const bf16x8*)&xb[(size_t)mload * IN_DIM + s * 32 + quad * 8];

    #pragma unroll
    for (int tt = 0; tt < 9; ++tt) {
        const unsigned short* Brow = (tt < 8) ? &w1t[(tt * 16 + l15) * IN_DIM]
                                              : &p1t[l15 * IN_DIM];
        f32x4 acc = {0.f, 0.f, 0.f, 0.f};
        #pragma unroll
        for (int s = 0; s < 4; ++s) {
            bf16x8 bf = *(const bf16x8*)&Brow[s * 32 + quad * 8];
            acc = __builtin_amdgcn_mfma_f32_16x16x32_bf16(af[s], bf, acc, 0, 0, 0);
        }
        int nodeb = n0 + quad * 4;
        if (tt < 8) {
            int ch = tt * 16 + l15;
            #pragma unroll
            for (int r = 0; r < 4; ++r)
                if (nodeb + r < N_NODES)
                    h1b[(size_t)(nodeb + r) * HID + ch] = f2bf(acc[r]);
        } else {
            #pragma unroll
            for (int r = 0; r < 4; ++r) {
                if (nodeb + r < N_NODES) {
                    if (l15 < 8) a_src[(nodeb + r) * HEADS + l15] = acc[r];
                    else         a_dst[(nodeb + r) * HEADS + (l15 - 8)] = acc[r];
                }
            }
        }
    }
}

// ---------------- Layer 1: aggregate ----------------
// 2 nodes per wave: lanes 0-31 node A, 32-63 node B; 4 bf16 channels/lane
// (dwordx2 gathers). Exhausted lanes contribute p = exp2(-1e4) = 0.

__global__ __launch_bounds__(128) void l1_aggregate(
        const unsigned short* __restrict__ h1b, const float* __restrict__ a_src,
        const float* __restrict__ a_dst, const int* __restrict__ row_start,
        const int* __restrict__ csr_src, const float* __restrict__ b1,
        unsigned short* __restrict__ h_act_b) {
    int t = threadIdx.x;
    int w = t >> 6;
    uint32 lane = t & 63;
    uint32 half = lane >> 5;
    uint32 lane32 = lane & 31;
    int n = blockIdx.x * 4 + w * 2 + (int)half;
    uint32 c0 = lane32 * 4u;     // 4 channels per lane
    uint32 h = lane32 >> 2;      // head = c0 >> 4
    int beg = row_start[n], end = row_start[n + 1];
    int cnt = end - beg;
    int kmax = cnt;
    #pragma unroll
    for (int m = 32; m > 0; m >>= 1) kmax = max(kmax, __shfl_xor(kmax, m, 64));
    float adst = a_dst[n * HEADS + h];
    float l = 0.f, a0 = 0.f, a1 = 0.f, a2 = 0.f, a3 = 0.f;

    for (int k = 0; k < kmax; k += 4) {
        uint32 ss[4]; float ee[4]; uint2 uu[4];
        #pragma unroll
        for (int q = 0; q < 4; ++q) {
            int j = beg + k + q;
            int jc = (j < end) ? j : (end - 1);    // cnt >= 1 (self loop)
            ss[q] = (uint32)csr_src[jc];
        }
        #pragma unroll
        for (int q = 0; q < 4; ++q) ee[q] = a_src[ss[q] * 8u + h];
        #pragma unroll
        for (int q = 0; q < 4; ++q) uu[q] = *(const uint2*)&h1b[(ss[q] << 7) + c0];
        #pragma unroll
        for (int q = 0; q < 4; ++q) {
            float e = ee[q] + adst;
            e = fmaxf(e, NEG_SLOPE * e);          // leaky relu (log2 domain)
            e = (k + q < cnt) ? e : -10000.f;     // masked lane -> p = 0
            float p = exp2f(e);
            l += p;
            a0 = fmaf(p, __uint_as_float(uu[q].x << 16), a0);
            a1 = fmaf(p, __uint_as_float(uu[q].x & 0xFFFF0000u), a1);
            a2 = fmaf(p, __uint_as_float(uu[q].y << 16), a2);
            a3 = fmaf(p, __uint_as_float(uu[q].y & 0xFFFF0000u), a3);
        }
    }

    float inv = 1.f / (l + 1e-16f);
    float v0 = a0 * inv + b1[c0];
    float v1 = a1 * inv + b1[c0 + 1];
    float v2 = a2 * inv + b1[c0 + 2];
    float v3 = a3 * inv + b1[c0 + 3];
    v0 = v0 > 0.f ? v0 : (__expf(v0) - 1.f);   // ELU
    v1 = v1 > 0.f ? v1 : (__expf(v1) - 1.f);
    v2 = v2 > 0.f ? v2 : (__expf(v2) - 1.f);
    v3 = v3 > 0.f ? v3 : (__expf(v3) - 1.f);
    uint2 packed;
    packed.x = (uint32)f2bf(v0) | ((uint32)f2bf(v1) << 16);
    packed.y = (uint32)f2bf(v2) | ((uint32)f2bf(v3) << 16);
    *(uint2*)&h_act_b[(size_t)n * HID + c0] = packed;
}

// ---------------- Layer 2: transform via MFMA, LDS-free ----------------

__global__ __launch_bounds__(256) void l2_transform_mfma(
        const unsigned short* __restrict__ h_act_b, const unsigned short* __restrict__ w2t,
        const unsigned short* __restrict__ p2t, unsigned short* __restrict__ h2b,
        float* __restrict__ a_src2, float* __restrict__ a_dst2) {
    int t = threadIdx.x, w = t >> 6, lane = t & 63;
    int l15 = lane & 15, quad = lane >> 4;
    int n0 = blockIdx.x * 64 + w * 16;
    int mrow = n0 + l15;
    int mload = (mrow < N_NODES) ? mrow : (N_NODES - 1);

    bf16x8 af[4];
    #pragma unroll
    for (int s = 0; s < 4; ++s)
        af[s] = *(const bf16x8*)&h_act_b[(size_t)mload * HID + s * 32 + quad * 8];

    #pragma unroll
    for (int tt = 0; tt < 5; ++tt) {
        const unsigned short* Brow = (tt < 4) ? &w2t[(tt * 16 + l15) * HID]
                                              : &p2t[l15 * HID];
        f32x4 acc = {0.f, 0.f, 0.f, 0.f};
        #pragma unroll
        for (int s = 0; s < 4; ++s) {
            bf16x8 bf = *(const bf16x8*)&Brow[s * 32 + quad * 8];
            acc = __builtin_amdgcn_mfma_f32_16x16x32_bf16(af[s], bf, acc, 0, 0, 0);
        }
        int nodeb = n0 + quad * 4;
        if (tt < 4) {
            int ch = tt * 16 + l15;
            #pragma unroll
            for (int r = 0; r < 4; ++r)
                if (nodeb + r < N_NODES)
                    h2b[(size_t)(nodeb + r) * OUT_DIM + ch] = f2bf(acc[r]);
        } else {
            #pragma unroll
            for (int r = 0; r < 4; ++r) {
                if (nodeb + r < N_NODES) {
                    if (l15 == 0) a_src2[nodeb + r] = acc[r];
                    else if (l15 == 1) a_dst2[nodeb + r] = acc[r];
                }
            }
        }
    }
}

// ---------------- Layer 2: aggregate + log_softmax ----------------
// 2 nodes per wave, 2 channels/lane (dword gathers).

__global__ __launch_bounds__(128) void l2_aggregate(
        const unsigned short* __restrict__ h2b, const float* __restrict__ a_src2,
        const float* __restrict__ a_dst2, const int* __restrict__ row_start,
        const int* __restrict__ csr_src, const float* __restrict__ b2,
        float* __restrict__ out) {
    int t = threadIdx.x;
    int w = t >> 6;
    uint32 lane = t & 63;
    uint32 half = lane >> 5;
    uint32 lane32 = lane & 31;
    int n = blockIdx.x * 4 + w * 2 + (int)half;
    uint32 c0 = lane32 * 2u;
    int beg = row_start[n], end = row_start[n + 1];
    int cnt = end - beg;
    int kmax = cnt;
    #pragma unroll
    for (int m = 32; m > 0; m >>= 1) kmax = max(kmax, __shfl_xor(kmax, m, 64));
    float adst = a_dst2[n];
    float l = 0.f, accx = 0.f, accy = 0.f;
    const uint32* h2w = (const uint32*)h2b;

    for (int k = 0; k < kmax; k += 4) {
        uint32 ss[4]; float ee[4]; uint32 uu[4];
        #pragma unroll
        for (int q = 0; q < 4; ++q) {
            int j = beg + k + q;
            int jc = (j < end) ? j : (end - 1);
            ss[q] = (uint32)csr_src[jc];
        }
        #pragma unroll
        for (int q = 0; q < 4; ++q) ee[q] = a_src2[ss[q]];
        #pragma unroll
        for (int q = 0; q < 4; ++q) uu[q] = h2w[(ss[q] << 5) + lane32];
        #pragma unroll
        for (int q = 0; q < 4; ++q) {
            float e = ee[q] + adst;
            e = fmaxf(e, NEG_SLOPE * e);
            e = (k + q < cnt) ? e : -10000.f;   // masked lane -> p = 0
            float p = exp2f(e);
            l += p;
            float vx = __uint_as_float(uu[q] << 16);
            float vy = __uint_as_float(uu[q] & 0xFFFF0000u);
            accx = fmaf(p, vx, accx);
            accy = fmaf(p, vy, accy);
        }
    }

    float inv = 1.f / (l + 1e-16f);
    float ox = accx * inv + b2[c0];
    float oy = accy * inv + b2[c0 + 1];
    // log_softmax over 64 channels = 32 lanes x 2 (half-wave reduction)
    float mx = fmaxf(ox, oy);
    #pragma unroll
    for (int m = 16; m > 0; m >>= 1) mx = fmaxf(mx, __shfl_xor(mx, m, 32));
    float ex = __expf(ox - mx) + __expf(oy - mx);
    #pragma unroll
    for (int m = 16; m > 0; m >>= 1) ex += __shfl_xor(ex, m, 32);
    float lse = mx + __logf(ex);
    float2 o = make_float2(ox - lse, oy - lse);
    *(float2*)&out[(size_t)n * OUT_DIM + c0] = o;
}

// ---------------- launch ----------------

extern "C" void kernel_launch(void* const* d_in, const int* in_sizes, int n_in,
                              void* d_out, int out_size, void* d_ws, size_t ws_size,
                              hipStream_t stream) {
    const float* x   = (const float*)d_in[0];
    const int*   ei  = (const int*)d_in[1];
    const float* W1  = (const float*)d_in[2];
    const float* as1 = (const float*)d_in[3];
    const float* ad1 = (const float*)d_in[4];
    const float* b1  = (const float*)d_in[5];
    const float* W2  = (const float*)d_in[6];
    const float* as2 = (const float*)d_in[7];
    const float* ad2 = (const float*)d_in[8];
    const float* b2  = (const float*)d_in[9];
    float* out = (float*)d_out;

    const int* src = ei;             // row 0
    const int* dst = ei + E_EDGES;   // row 1

    char* ws = (char*)d_ws;
    size_t off = 0;
    auto alloc = [&](size_t bytes) -> void* {
        void* p = ws + off;
        off += (bytes + 255) & ~size_t(255);
        return p;
    };
    unsigned short* xb     = (unsigned short*)alloc((size_t)N_NODES * IN_DIM * 2);
    unsigned short* h1b    = (unsigned short*)alloc((size_t)N_NODES * HID * 2);
    unsigned short* h_act_b= (unsigned short*)alloc((size_t)N_NODES * HID * 2);
    unsigned short* h2b    = (unsigned short*)alloc((size_t)N_NODES * OUT_DIM * 2);
    unsigned short* w1t    = (unsigned short*)alloc((size_t)HID * IN_DIM * 2);
    unsigned short* p1t    = (unsigned short*)alloc((size_t)16 * IN_DIM * 2);
    unsigned short* w2t    = (unsigned short*)alloc((size_t)OUT_DIM * HID * 2);
    unsigned short* p2t    = (unsigned short*)alloc((size_t)16 * HID * 2);
    float* a_src1    = (float*)alloc((size_t)N_NODES * HEADS * 4);
    float* a_dst1    = (float*)alloc((size_t)N_NODES * HEADS * 4);
    float* a_src2    = (float*)alloc((size_t)N_NODES * 4);
    float* a_dst2    = (float*)alloc((size_t)N_NODES * 4);
    int*   row_start = (int*)alloc((size_t)(N_NODES + 1) * 4);
    int*   csr_src   = (int*)alloc((size_t)ET * 4);
    uint32* pairs    = (uint32*)alloc((size_t)ET * 4);
    int*   cnt       = (int*)alloc((size_t)NB * NT * 4);
    int*   bucketStart = (int*)alloc((size_t)(NB + 1) * 4);

    prep_all<<<MEGA_A, 256, 0, stream>>>(dst, cnt, x, xb, W1, as1, ad1,
                                         W2, as2, ad2, w1t, p1t, w2t, p2t);
    bucket_scatter<<<NT, 256, 0, stream>>>(src, dst, cnt, bucketStart, pairs);
    build_l1t<<<MEGA_B, 256, 0, stream>>>(pairs, bucketStart, row_start, csr_src,
                                          xb, w1t, p1t, h1b, a_src1, a_dst1);
    l1_aggregate<<<N_NODES / 4, 128, 0, stream>>>(h1b, a_src1, a_dst1, row_start, csr_src, b1, h_act_b);
    l2_transform_mfma<<<L1T_BLOCKS, 256, 0, stream>>>(h_act_b, w2t, p2t, h2b, a_src2, a_dst2);
    l2_aggregate<<<N_NODES / 4, 128, 0, stream>>>(h2b, a_src2, a_dst2, row_start, csr_src, b2, out);
}

// Round 14
// 219.233 us; speedup vs baseline: 2.9900x; 1.0124x over previous
//
#include <hip/hip_runtime.h>
#include <math.h>

#define N_NODES 50000
#define E_EDGES 800000
#define ET      (E_EDGES + N_NODES)   // edges + self loops
#define IN_DIM  128
#define HID     128
#define HEADS   8
#define C1      16
#define OUT_DIM 64
#define NEG_SLOPE 0.2f
#define LOG2E   1.4426950408889634f

#define TILE    8192
#define NT      ((ET + TILE - 1) / TILE)      // 104 tiles
#define NB      ((N_NODES + 255) / 256)       // 196 buckets of 256 nodes

#define CONV_BLOCKS (N_NODES * IN_DIM / 4 / 256)   // 6250
#define PREP_BLOCKS 112
#define MEGA_A (NT + CONV_BLOCKS + PREP_BLOCKS)    // 6466
#define L1T_BLOCKS ((N_NODES + 63) / 64)           // 782
#define MEGA_B (NB + L1T_BLOCKS)                   // 978

typedef unsigned int uint32;
typedef __attribute__((ext_vector_type(8))) short bf16x8;
typedef __attribute__((ext_vector_type(4))) float f32x4;

static __device__ __forceinline__ unsigned short f2bf(float f) {
    uint32 u = __float_as_uint(f);
    u += 0x7FFFu + ((u >> 16) & 1u);   // round to nearest even
    return (unsigned short)(u >> 16);
}

// ---------------- Mega-kernel A: bucket_hist + convert_x + prep_weights ----------------
// cnt layout [NT][NB] so prefix recompute reads coalesced across lanes.
// p1t/p2t rows are pre-scaled by log2(e) so aggregates use bare exp2f.

__global__ __launch_bounds__(256) void prep_all(
        const int* __restrict__ dst, int* __restrict__ cnt,
        const float* __restrict__ x, unsigned short* __restrict__ xb,
        const float* __restrict__ W1, const float* __restrict__ as1,
        const float* __restrict__ ad1, const float* __restrict__ W2,
        const float* __restrict__ as2, const float* __restrict__ ad2,
        unsigned short* __restrict__ w1t, unsigned short* __restrict__ p1t,
        unsigned short* __restrict__ w2t, unsigned short* __restrict__ p2t) {
    __shared__ int hist[NB];
    int blk = blockIdx.x, t = threadIdx.x;
    if (blk < NT) {
        for (int b = t; b < NB; b += 256) hist[b] = 0;
        __syncthreads();
        int base = blk * TILE;
        #pragma unroll
        for (int it = 0; it < TILE / 256; ++it) {
            int i = base + it * 256 + t;
            if (i < ET) {
                int d = (i < E_EDGES) ? dst[i] : (i - E_EDGES);
                atomicAdd(&hist[d >> 8], 1);
            }
        }
        __syncthreads();
        for (int b = t; b < NB; b += 256) cnt[blk * NB + b] = hist[b];
    } else if (blk < NT + CONV_BLOCKS) {
        int i = (blk - NT) * 256 + t;
        float4 v = ((const float4*)x)[i];
        ushort4 o;
        o.x = f2bf(v.x); o.y = f2bf(v.y); o.z = f2bf(v.z); o.w = f2bf(v.w);
        ((ushort4*)xb)[i] = o;
    } else {
        int b = blk - NT - CONV_BLOCKS;    // 0..111
        if (b < 64) {
            int i = b * 256 + t;                // n*128+k
            int n = i >> 7, k = i & 127;
            w1t[n * IN_DIM + k] = f2bf(W1[k * HID + n]);
        } else if (b < 96) {
            int i = (b - 64) * 256 + t;         // n*128+k, n<64
            int n = i >> 7, k = i & 127;
            w2t[n * HID + k] = f2bf(W2[k * OUT_DIM + n]);
        } else if (b < 104) {
            int i = (b - 96) * 256 + t;         // j*128+k, j<16
            int j = i >> 7, k = i & 127;
            int hh = j & 7;
            const float* a = (j < 8) ? as1 : ad1;
            float acc = 0.f;
            #pragma unroll
            for (int c = 0; c < C1; ++c)
                acc = fmaf(W1[k * HID + hh * C1 + c], a[hh * C1 + c], acc);
            p1t[j * IN_DIM + k] = f2bf(acc * LOG2E);
        } else {
            int i = (b - 104) * 256 + t;        // j*128+k, j<16
            int j = i >> 7, k = i & 127;
            if (j < 2) {
                const float* a = (j == 0) ? as2 : ad2;
                float acc = 0.f;
                #pragma unroll
                for (int c = 0; c < OUT_DIM; ++c)
                    acc = fmaf(W2[k * OUT_DIM + c], a[c], acc);
                p2t[j * HID + k] = f2bf(acc * LOG2E);
            } else {
                p2t[j * HID + k] = 0;
            }
        }
    }
}

// ---------------- bucket_scatter (scan fused in) ----------------

__global__ __launch_bounds__(256) void bucket_scatter(
        const int* __restrict__ src, const int* __restrict__ dst,
        const int* __restrict__ cnt, int* __restrict__ bucketStart,
        uint32* __restrict__ pairs) {
    __shared__ int lcur[NB];
    __shared__ int sscan[256];
    int t = threadIdx.x;
    int tile = blockIdx.x;

    int run = 0, total = 0;
    if (t < NB) {
        for (int k = 0; k < NT; ++k) {
            int c = cnt[k * NB + t];     // coalesced across t
            if (k < tile) run += c;
            total += c;
        }
    }
    sscan[t] = (t < NB) ? total : 0;
    __syncthreads();
    #pragma unroll
    for (int off = 1; off < 256; off <<= 1) {
        int add = (t >= off) ? sscan[t - off] : 0;
        __syncthreads();
        sscan[t] += add;
        __syncthreads();
    }
    int bstart = sscan[t] - total;       // exclusive prefix
    if (t < NB) {
        lcur[t] = bstart + run;
        if (tile == 0) bucketStart[t] = bstart;
    }
    if (tile == 0 && t == 0) bucketStart[NB] = ET;
    __syncthreads();

    int base = tile * TILE;
    #pragma unroll
    for (int it = 0; it < TILE / 256; ++it) {
        int i = base + it * 256 + t;
        if (i < ET) {
            int s, d;
            if (i < E_EDGES) { s = src[i]; d = dst[i]; }
            else             { s = d = i - E_EDGES; }
            int pos = atomicAdd(&lcur[d >> 8], 1);
            pairs[pos] = ((uint32)s << 8) | (uint32)(d & 255);
        }
    }
}

// ---------------- Mega-kernel B: bucket_build + l1_transform_mfma ----------------

__global__ __launch_bounds__(256) void build_l1t(
        const uint32* __restrict__ pairs, const int* __restrict__ bucketStart,
        int* __restrict__ row_start, int* __restrict__ csr_src,
        const unsigned short* __restrict__ xb, const unsigned short* __restrict__ w1t,
        const unsigned short* __restrict__ p1t, unsigned short* __restrict__ h1b,
        float* __restrict__ a_src, float* __restrict__ a_dst) {
    __shared__ int sdeg[256];
    __shared__ int sscan[256];
    int t = threadIdx.x;
    if (blockIdx.x < NB) {
        int b = blockIdx.x;
        int beg = bucketStart[b], end = bucketStart[b + 1];
        sdeg[t] = 0;
        __syncthreads();
        for (int j = beg + t; j < end; j += 256)
            atomicAdd(&sdeg[pairs[j] & 255u], 1);
        __syncthreads();
        int v = sdeg[t];
        sscan[t] = v;
        __syncthreads();
        #pragma unroll
        for (int off = 1; off < 256; off <<= 1) {
            int add = (t >= off) ? sscan[t - off] : 0;
            __syncthreads();
            sscan[t] += add;
            __syncthreads();
        }
        int pos0 = beg + sscan[t] - v;   // exclusive prefix within bucket
        int n = b * 256 + t;
        if (n < N_NODES) row_start[n] = pos0;
        if (b == 0 && t == 0) row_start[N_NODES] = ET;
        __syncthreads();
        sscan[t] = pos0;                 // reuse as cursor
        __syncthreads();
        for (int j = beg + t; j < end; j += 256) {
            uint32 p = pairs[j];
            int pos = atomicAdd(&sscan[p & 255u], 1);
            csr_src[pos] = (int)(p >> 8);
        }
        return;
    }
    // ---- layer-1 transform via MFMA, LDS-free ----
    int bb = blockIdx.x - NB;
    int w = t >> 6, lane = t & 63;
    int l15 = lane & 15, quad = lane >> 4;
    int n0 = bb * 64 + w * 16;
    int mrow = n0 + l15;
    int mload = (mrow < N_NODES) ? mrow : (N_NODES - 1);

    bf16x8 af[4];
    #pragma unroll
    for (int s = 0; s < 4; ++s)
        af[s] = *(const bf16x8*)&xb[(size_t)mload * IN_DIM + s * 32 + quad * 8];

    #pragma unroll
    for (int tt = 0; tt < 9; ++tt) {
        const unsigned short* Brow = (tt < 8) ? &w1t[(tt * 16 + l15) * IN_DIM]
                                              : &p1t[l15 * IN_DIM];
        f32x4 acc = {0.f, 0.f, 0.f, 0.f};
        #pragma unroll
        for (int s = 0; s < 4; ++s) {
            bf16x8 bf = *(const bf16x8*)&Brow[s * 32 + quad * 8];
            acc = __builtin_amdgcn_mfma_f32_16x16x32_bf16(af[s], bf, acc, 0, 0, 0);
        }
        int nodeb = n0 + quad * 4;
        if (tt < 8) {
            int ch = tt * 16 + l15;
            #pragma unroll
            for (int r = 0; r < 4; ++r)
                if (nodeb + r < N_NODES)
                    h1b[(size_t)(nodeb + r) * HID + ch] = f2bf(acc[r]);
        } else {
            #pragma unroll
            for (int r = 0; r < 4; ++r) {
                if (nodeb + r < N_NODES) {
                    if (l15 < 8) a_src[(nodeb + r) * HEADS + l15] = acc[r];
                    else         a_dst[(nodeb + r) * HEADS + (l15 - 8)] = acc[r];
                }
            }
        }
    }
}

// ---------------- Layer 1: aggregate ----------------
// 4 nodes per wave: 16 lanes per node, 8 bf16 channels/lane (uint4 16B gathers).
// Exhausted lanes contribute p = exp2(-1e4) = 0.

__global__ __launch_bounds__(128) void l1_aggregate(
        const unsigned short* __restrict__ h1b, const float* __restrict__ a_src,
        const float* __restrict__ a_dst, const int* __restrict__ row_start,
        const int* __restrict__ csr_src, const float* __restrict__ b1,
        unsigned short* __restrict__ h_act_b) {
    int t = threadIdx.x;
    int w = t >> 6;
    uint32 lane = t & 63;
    uint32 quarter = lane >> 4;
    uint32 lane16 = lane & 15;
    int n = blockIdx.x * 8 + w * 4 + (int)quarter;
    uint32 c0 = lane16 * 8u;     // 8 channels per lane
    uint32 h = lane16 >> 1;      // head = c0 >> 4
    int beg = row_start[n], end = row_start[n + 1];
    int cnt = end - beg;
    int kmax = cnt;
    kmax = max(kmax, __shfl_xor(kmax, 16, 64));
    kmax = max(kmax, __shfl_xor(kmax, 32, 64));
    float adst = a_dst[n * HEADS + h];
    float l = 0.f;
    float a0 = 0.f, a1 = 0.f, a2 = 0.f, a3 = 0.f;
    float a4 = 0.f, a5 = 0.f, a6 = 0.f, a7 = 0.f;

    for (int k = 0; k < kmax; k += 4) {
        uint32 ss[4]; float ee[4]; uint4 uu[4];
        #pragma unroll
        for (int q = 0; q < 4; ++q) {
            int j = beg + k + q;
            int jc = (j < end) ? j : (end - 1);    // cnt >= 1 (self loop)
            ss[q] = (uint32)csr_src[jc];
        }
        #pragma unroll
        for (int q = 0; q < 4; ++q) ee[q] = a_src[ss[q] * 8u + h];
        #pragma unroll
        for (int q = 0; q < 4; ++q) uu[q] = *(const uint4*)&h1b[(ss[q] << 7) + c0];
        #pragma unroll
        for (int q = 0; q < 4; ++q) {
            float e = ee[q] + adst;
            e = fmaxf(e, NEG_SLOPE * e);          // leaky relu (log2 domain)
            e = (k + q < cnt) ? e : -10000.f;     // masked lane -> p = 0
            float p = exp2f(e);
            l += p;
            a0 = fmaf(p, __uint_as_float(uu[q].x << 16), a0);
            a1 = fmaf(p, __uint_as_float(uu[q].x & 0xFFFF0000u), a1);
            a2 = fmaf(p, __uint_as_float(uu[q].y << 16), a2);
            a3 = fmaf(p, __uint_as_float(uu[q].y & 0xFFFF0000u), a3);
            a4 = fmaf(p, __uint_as_float(uu[q].z << 16), a4);
            a5 = fmaf(p, __uint_as_float(uu[q].z & 0xFFFF0000u), a5);
            a6 = fmaf(p, __uint_as_float(uu[q].w << 16), a6);
            a7 = fmaf(p, __uint_as_float(uu[q].w & 0xFFFF0000u), a7);
        }
    }

    float inv = 1.f / (l + 1e-16f);
    float v0 = a0 * inv + b1[c0 + 0];
    float v1 = a1 * inv + b1[c0 + 1];
    float v2 = a2 * inv + b1[c0 + 2];
    float v3 = a3 * inv + b1[c0 + 3];
    float v4 = a4 * inv + b1[c0 + 4];
    float v5 = a5 * inv + b1[c0 + 5];
    float v6 = a6 * inv + b1[c0 + 6];
    float v7 = a7 * inv + b1[c0 + 7];
    v0 = v0 > 0.f ? v0 : (__expf(v0) - 1.f);   // ELU
    v1 = v1 > 0.f ? v1 : (__expf(v1) - 1.f);
    v2 = v2 > 0.f ? v2 : (__expf(v2) - 1.f);
    v3 = v3 > 0.f ? v3 : (__expf(v3) - 1.f);
    v4 = v4 > 0.f ? v4 : (__expf(v4) - 1.f);
    v5 = v5 > 0.f ? v5 : (__expf(v5) - 1.f);
    v6 = v6 > 0.f ? v6 : (__expf(v6) - 1.f);
    v7 = v7 > 0.f ? v7 : (__expf(v7) - 1.f);
    uint4 packed;
    packed.x = (uint32)f2bf(v0) | ((uint32)f2bf(v1) << 16);
    packed.y = (uint32)f2bf(v2) | ((uint32)f2bf(v3) << 16);
    packed.z = (uint32)f2bf(v4) | ((uint32)f2bf(v5) << 16);
    packed.w = (uint32)f2bf(v6) | ((uint32)f2bf(v7) << 16);
    *(uint4*)&h_act_b[(size_t)n * HID + c0] = packed;
}

// ---------------- Layer 2: transform via MFMA, LDS-free ----------------

__global__ __launch_bounds__(256) void l2_transform_mfma(
        const unsigned short* __restrict__ h_act_b, const unsigned short* __restrict__ w2t,
        const unsigned short* __restrict__ p2t, unsigned short* __restrict__ h2b,
        float* __restrict__ a_src2, float* __restrict__ a_dst2) {
    int t = threadIdx.x, w = t >> 6, lane = t & 63;
    int l15 = lane & 15, quad = lane >> 4;
    int n0 = blockIdx.x * 64 + w * 16;
    int mrow = n0 + l15;
    int mload = (mrow < N_NODES) ? mrow : (N_NODES - 1);

    bf16x8 af[4];
    #pragma unroll
    for (int s = 0; s < 4; ++s)
        af[s] = *(const bf16x8*)&h_act_b[(size_t)mload * HID + s * 32 + quad * 8];

    #pragma unroll
    for (int tt = 0; tt < 5; ++tt) {
        const unsigned short* Brow = (tt < 4) ? &w2t[(tt * 16 + l15) * HID]
                                              : &p2t[l15 * HID];
        f32x4 acc = {0.f, 0.f, 0.f, 0.f};
        #pragma unroll
        for (int s = 0; s < 4; ++s) {
            bf16x8 bf = *(const bf16x8*)&Brow[s * 32 + quad * 8];
            acc = __builtin_amdgcn_mfma_f32_16x16x32_bf16(af[s], bf, acc, 0, 0, 0);
        }
        int nodeb = n0 + quad * 4;
        if (tt < 4) {
            int ch = tt * 16 + l15;
            #pragma unroll
            for (int r = 0; r < 4; ++r)
                if (nodeb + r < N_NODES)
                    h2b[(size_t)(nodeb + r) * OUT_DIM + ch] = f2bf(acc[r]);
        } else {
            #pragma unroll
            for (int r = 0; r < 4; ++r) {
                if (nodeb + r < N_NODES) {
                    if (l15 == 0) a_src2[nodeb + r] = acc[r];
                    else if (l15 == 1) a_dst2[nodeb + r] = acc[r];
                }
            }
        }
    }
}

// ---------------- Layer 2: aggregate + log_softmax ----------------
// 4 nodes per wave: 16 lanes per node, 4 channels/lane (uint2 gathers).

__global__ __launch_bounds__(128) void l2_aggregate(
        const unsigned short* __restrict__ h2b, const float* __restrict__ a_src2,
        const float* __restrict__ a_dst2, const int* __restrict__ row_start,
        const int* __restrict__ csr_src, const float* __restrict__ b2,
        float* __restrict__ out) {
    int t = threadIdx.x;
    int w = t >> 6;
    uint32 lane = t & 63;
    uint32 quarter = lane >> 4;
    uint32 lane16 = lane & 15;
    int n = blockIdx.x * 8 + w * 4 + (int)quarter;
    uint32 c0 = lane16 * 4u;
    int beg = row_start[n], end = row_start[n + 1];
    int cnt = end - beg;
    int kmax = cnt;
    kmax = max(kmax, __shfl_xor(kmax, 16, 64));
    kmax = max(kmax, __shfl_xor(kmax, 32, 64));
    float adst = a_dst2[n];
    float l = 0.f, a0 = 0.f, a1 = 0.f, a2 = 0.f, a3 = 0.f;

    for (int k = 0; k < kmax; k += 4) {
        uint32 ss[4]; float ee[4]; uint2 uu[4];
        #pragma unroll
        for (int q = 0; q < 4; ++q) {
            int j = beg + k + q;
            int jc = (j < end) ? j : (end - 1);
            ss[q] = (uint32)csr_src[jc];
        }
        #pragma unroll
        for (int q = 0; q < 4; ++q) ee[q] = a_src2[ss[q]];
        #pragma unroll
        for (int q = 0; q < 4; ++q) uu[q] = *(const uint2*)&h2b[(ss[q] << 6) + c0];
        #pragma unroll
        for (int q = 0; q < 4; ++q) {
            float e = ee[q] + adst;
            e = fmaxf(e, NEG_SLOPE * e);
            e = (k + q < cnt) ? e : -10000.f;   // masked lane -> p = 0
            float p = exp2f(e);
            l += p;
            a0 = fmaf(p, __uint_as_float(uu[q].x << 16), a0);
            a1 = fmaf(p, __uint_as_float(uu[q].x & 0xFFFF0000u), a1);
            a2 = fmaf(p, __uint_as_float(uu[q].y << 16), a2);
            a3 = fmaf(p, __uint_as_float(uu[q].y & 0xFFFF0000u), a3);
        }
    }

    float inv = 1.f / (l + 1e-16f);
    float o0 = a0 * inv + b2[c0 + 0];
    float o1 = a1 * inv + b2[c0 + 1];
    float o2 = a2 * inv + b2[c0 + 2];
    float o3 = a3 * inv + b2[c0 + 3];
    // log_softmax over 64 channels = 16 lanes x 4 (quarter-wave reduction)
    float mx = fmaxf(fmaxf(o0, o1), fmaxf(o2, o3));
    #pragma unroll
    for (int m = 8; m > 0; m >>= 1) mx = fmaxf(mx, __shfl_xor(mx, m, 16));
    float ex = __expf(o0 - mx) + __expf(o1 - mx) + __expf(o2 - mx) + __expf(o3 - mx);
    #pragma unroll
    for (int m = 8; m > 0; m >>= 1) ex += __shfl_xor(ex, m, 16);
    float lse = mx + __logf(ex);
    float4 o = make_float4(o0 - lse, o1 - lse, o2 - lse, o3 - lse);
    *(float4*)&out[(size_t)n * OUT_DIM + c0] = o;
}

// ---------------- launch ----------------

extern "C" void kernel_launch(void* const* d_in, const int* in_sizes, int n_in,
                              void* d_out, int out_size, void* d_ws, size_t ws_size,
                              hipStream_t stream) {
    const float* x   = (const float*)d_in[0];
    const int*   ei  = (const int*)d_in[1];
    const float* W1  = (const float*)d_in[2];
    const float* as1 = (const float*)d_in[3];
    const float* ad1 = (const float*)d_in[4];
    const float* b1  = (const float*)d_in[5];
    const float* W2  = (const float*)d_in[6];
    const float* as2 = (const float*)d_in[7];
    const float* ad2 = (const float*)d_in[8];
    const float* b2  = (const float*)d_in[9];
    float* out = (float*)d_out;

    const int* src = ei;             // row 0
    const int* dst = ei + E_EDGES;   // row 1

    char* ws = (char*)d_ws;
    size_t off = 0;
    auto alloc = [&](size_t bytes) -> void* {
        void* p = ws + off;
        off += (bytes + 255) & ~size_t(255);
        return p;
    };
    unsigned short* xb     = (unsigned short*)alloc((size_t)N_NODES * IN_DIM * 2);
    unsigned short* h1b    = (unsigned short*)alloc((size_t)N_NODES * HID * 2);
    unsigned short* h_act_b= (unsigned short*)alloc((size_t)N_NODES * HID * 2);
    unsigned short* h2b    = (unsigned short*)alloc((size_t)N_NODES * OUT_DIM * 2);
    unsigned short* w1t    = (unsigned short*)alloc((size_t)HID * IN_DIM * 2);
    unsigned short* p1t    = (unsigned short*)alloc((size_t)16 * IN_DIM * 2);
    unsigned short* w2t    = (unsigned short*)alloc((size_t)OUT_DIM * HID * 2);
    unsigned short* p2t    = (unsigned short*)alloc((size_t)16 * HID * 2);
    float* a_src1    = (float*)alloc((size_t)N_NODES * HEADS * 4);
    float* a_dst1    = (float*)alloc((size_t)N_NODES * HEADS * 4);
    float* a_src2    = (float*)alloc((size_t)N_NODES * 4);
    float* a_dst2    = (float*)alloc((size_t)N_NODES * 4);
    int*   row_start = (int*)alloc((size_t)(N_NODES + 1) * 4);
    int*   csr_src   = (int*)alloc((size_t)ET * 4);
    uint32* pairs    = (uint32*)alloc((size_t)ET * 4);
    int*   cnt       = (int*)alloc((size_t)NB * NT * 4);
    int*   bucketStart = (int*)alloc((size_t)(NB + 1) * 4);

    prep_all<<<MEGA_A, 256, 0, stream>>>(dst, cnt, x, xb, W1, as1, ad1,
                                         W2, as2, ad2, w1t, p1t, w2t, p2t);
    bucket_scatter<<<NT, 256, 0, stream>>>(src, dst, cnt, bucketStart, pairs);
    build_l1t<<<MEGA_B, 256, 0, stream>>>(pairs, bucketStart, row_start, csr_src,
                                          xb, w1t, p1t, h1b, a_src1, a_dst1);
    l1_aggregate<<<N_NODES / 8, 128, 0, stream>>>(h1b, a_src1, a_dst1, row_start, csr_src, b1, h_act_b);
    l2_transform_mfma<<<L1T_BLOCKS, 256, 0, stream>>>(h_act_b, w2t, p2t, h2b, a_src2, a_dst2);
    l2_aggregate<<<N_NODES / 8, 128, 0, stream>>>(h2b, a_src2, a_dst2, row_start, csr_src, b2, out);
}

// Round 15
// 212.557 us; speedup vs baseline: 3.0839x; 1.0314x over previous
//
#include <hip/hip_runtime.h>
#include <math.h>

#define N_NODES 50000
#define E_EDGES 800000
#define ET      (E_EDGES + N_NODES)   // edges + self loops
#define IN_DIM  128
#define HID     128
#define HEADS   8
#define C1      16
#define OUT_DIM 64
#define NEG_SLOPE 0.2f
#define LOG2E   1.4426950408889634f

#define TILE    8192
#define NT      ((ET + TILE - 1) / TILE)      // 104 tiles
#define NB      ((N_NODES + 255) / 256)       // 196 buckets of 256 nodes

#define CONV_BLOCKS (N_NODES * IN_DIM / 4 / 256)   // 6250
#define PREP_BLOCKS 112
#define MEGA_A (NT + CONV_BLOCKS + PREP_BLOCKS)    // 6466
#define L1T_BLOCKS ((N_NODES + 63) / 64)           // 782
#define MEGA_B (NB + L1T_BLOCKS)                   // 978

typedef unsigned int uint32;
typedef __attribute__((ext_vector_type(8))) short bf16x8;
typedef __attribute__((ext_vector_type(4))) float f32x4;

static __device__ __forceinline__ unsigned short f2bf(float f) {
    uint32 u = __float_as_uint(f);
    u += 0x7FFFu + ((u >> 16) & 1u);   // round to nearest even
    return (unsigned short)(u >> 16);
}

// ---------------- Mega-kernel A: bucket_hist + convert_x + prep_weights ----------------

__global__ __launch_bounds__(256) void prep_all(
        const int* __restrict__ dst, int* __restrict__ cnt,
        const float* __restrict__ x, unsigned short* __restrict__ xb,
        const float* __restrict__ W1, const float* __restrict__ as1,
        const float* __restrict__ ad1, const float* __restrict__ W2,
        const float* __restrict__ as2, const float* __restrict__ ad2,
        unsigned short* __restrict__ w1t, unsigned short* __restrict__ p1t,
        unsigned short* __restrict__ w2t, unsigned short* __restrict__ p2t) {
    __shared__ int hist[NB];
    int blk = blockIdx.x, t = threadIdx.x;
    if (blk < NT) {
        for (int b = t; b < NB; b += 256) hist[b] = 0;
        __syncthreads();
        int base = blk * TILE;
        #pragma unroll
        for (int it = 0; it < TILE / 256; ++it) {
            int i = base + it * 256 + t;
            if (i < ET) {
                int d = (i < E_EDGES) ? dst[i] : (i - E_EDGES);
                atomicAdd(&hist[d >> 8], 1);
            }
        }
        __syncthreads();
        for (int b = t; b < NB; b += 256) cnt[blk * NB + b] = hist[b];
    } else if (blk < NT + CONV_BLOCKS) {
        int i = (blk - NT) * 256 + t;
        float4 v = ((const float4*)x)[i];
        ushort4 o;
        o.x = f2bf(v.x); o.y = f2bf(v.y); o.z = f2bf(v.z); o.w = f2bf(v.w);
        ((ushort4*)xb)[i] = o;
    } else {
        int b = blk - NT - CONV_BLOCKS;    // 0..111
        if (b < 64) {
            int i = b * 256 + t;                // n*128+k
            int n = i >> 7, k = i & 127;
            w1t[n * IN_DIM + k] = f2bf(W1[k * HID + n]);
        } else if (b < 96) {
            int i = (b - 64) * 256 + t;         // n*128+k, n<64
            int n = i >> 7, k = i & 127;
            w2t[n * HID + k] = f2bf(W2[k * OUT_DIM + n]);
        } else if (b < 104) {
            int i = (b - 96) * 256 + t;         // j*128+k, j<16
            int j = i >> 7, k = i & 127;
            int hh = j & 7;
            const float* a = (j < 8) ? as1 : ad1;
            float acc = 0.f;
            #pragma unroll
            for (int c = 0; c < C1; ++c)
                acc = fmaf(W1[k * HID + hh * C1 + c], a[hh * C1 + c], acc);
            p1t[j * IN_DIM + k] = f2bf(acc * LOG2E);
        } else {
            int i = (b - 104) * 256 + t;        // j*128+k, j<16
            int j = i >> 7, k = i & 127;
            if (j < 2) {
                const float* a = (j == 0) ? as2 : ad2;
                float acc = 0.f;
                #pragma unroll
                for (int c = 0; c < OUT_DIM; ++c)
                    acc = fmaf(W2[k * OUT_DIM + c], a[c], acc);
                p2t[j * HID + k] = f2bf(acc * LOG2E);
            } else {
                p2t[j * HID + k] = 0;
            }
        }
    }
}

// ---------------- bucket_scatter (scan fused in) ----------------

__global__ __launch_bounds__(256) void bucket_scatter(
        const int* __restrict__ src, const int* __restrict__ dst,
        const int* __restrict__ cnt, int* __restrict__ bucketStart,
        uint32* __restrict__ pairs) {
    __shared__ int lcur[NB];
    __shared__ int sscan[256];
    int t = threadIdx.x;
    int tile = blockIdx.x;

    int run = 0, total = 0;
    if (t < NB) {
        for (int k = 0; k < NT; ++k) {
            int c = cnt[k * NB + t];     // coalesced across t
            if (k < tile) run += c;
            total += c;
        }
    }
    sscan[t] = (t < NB) ? total : 0;
    __syncthreads();
    #pragma unroll
    for (int off = 1; off < 256; off <<= 1) {
        int add = (t >= off) ? sscan[t - off] : 0;
        __syncthreads();
        sscan[t] += add;
        __syncthreads();
    }
    int bstart = sscan[t] - total;       // exclusive prefix
    if (t < NB) {
        lcur[t] = bstart + run;
        if (tile == 0) bucketStart[t] = bstart;
    }
    if (tile == 0 && t == 0) bucketStart[NB] = ET;
    __syncthreads();

    int base = tile * TILE;
    #pragma unroll
    for (int it = 0; it < TILE / 256; ++it) {
        int i = base + it * 256 + t;
        if (i < ET) {
            int s, d;
            if (i < E_EDGES) { s = src[i]; d = dst[i]; }
            else             { s = d = i - E_EDGES; }
            int pos = atomicAdd(&lcur[d >> 8], 1);
            pairs[pos] = ((uint32)s << 8) | (uint32)(d & 255);
        }
    }
}

// ---------------- Mega-kernel B: bucket_build + l1_transform_mfma ----------------

__global__ __launch_bounds__(256) void build_l1t(
        const uint32* __restrict__ pairs, const int* __restrict__ bucketStart,
        int* __restrict__ row_start, int* __restrict__ csr_src,
        const unsigned short* __restrict__ xb, const unsigned short* __restrict__ w1t,
        const unsigned short* __restrict__ p1t, unsigned short* __restrict__ h1b,
        float* __restrict__ a_src, float* __restrict__ a_dst) {
    __shared__ int sdeg[256];
    __shared__ int sscan[256];
    int t = threadIdx.x;
    if (blockIdx.x < NB) {
        int b = blockIdx.x;
        int beg = bucketStart[b], end = bucketStart[b + 1];
        sdeg[t] = 0;
        __syncthreads();
        for (int j = beg + t; j < end; j += 256)
            atomicAdd(&sdeg[pairs[j] & 255u], 1);
        __syncthreads();
        int v = sdeg[t];
        sscan[t] = v;
        __syncthreads();
        #pragma unroll
        for (int off = 1; off < 256; off <<= 1) {
            int add = (t >= off) ? sscan[t - off] : 0;
            __syncthreads();
            sscan[t] += add;
            __syncthreads();
        }
        int pos0 = beg + sscan[t] - v;   // exclusive prefix within bucket
        int n = b * 256 + t;
        if (n < N_NODES) row_start[n] = pos0;
        if (b == 0 && t == 0) row_start[N_NODES] = ET;
        __syncthreads();
        sscan[t] = pos0;                 // reuse as cursor
        __syncthreads();
        for (int j = beg + t; j < end; j += 256) {
            uint32 p = pairs[j];
            int pos = atomicAdd(&sscan[p & 255u], 1);
            csr_src[pos] = (int)(p >> 8);
        }
        return;
    }
    // ---- layer-1 transform via MFMA, LDS-free ----
    int bb = blockIdx.x - NB;
    int w = t >> 6, lane = t & 63;
    int l15 = lane & 15, quad = lane >> 4;
    int n0 = bb * 64 + w * 16;
    int mrow = n0 + l15;
    int mload = (mrow < N_NODES) ? mrow : (N_NODES - 1);

    bf16x8 af[4];
    #pragma unroll
    for (int s = 0; s < 4; ++s)
        af[s] = *(const bf16x8*)&xb[(size_t)mload * IN_DIM + s * 32 + quad * 8];

    #pragma unroll
    for (int tt = 0; tt < 9; ++tt) {
        const unsigned short* Brow = (tt < 8) ? &w1t[(tt * 16 + l15) * IN_DIM]
                                              : &p1t[l15 * IN_DIM];
        f32x4 acc = {0.f, 0.f, 0.f, 0.f};
        #pragma unroll
        for (int s = 0; s < 4; ++s) {
            bf16x8 bf = *(const bf16x8*)&Brow[s * 32 + quad * 8];
            acc = __builtin_amdgcn_mfma_f32_16x16x32_bf16(af[s], bf, acc, 0, 0, 0);
        }
        int nodeb = n0 + quad * 4;
        if (tt < 8) {
            int ch = tt * 16 + l15;
            #pragma unroll
            for (int r = 0; r < 4; ++r)
                if (nodeb + r < N_NODES)
                    h1b[(size_t)(nodeb + r) * HID + ch] = f2bf(acc[r]);
        } else {
            #pragma unroll
            for (int r = 0; r < 4; ++r) {
                if (nodeb + r < N_NODES) {
                    if (l15 < 8) a_src[(nodeb + r) * HEADS + l15] = acc[r];
                    else         a_dst[(nodeb + r) * HEADS + (l15 - 8)] = acc[r];
                }
            }
        }
    }
}

// ---------------- Fused: layer-1 aggregate + layer-2 transform ----------------
// One 256-thread block covers 64 nodes. Phase A: each wave aggregates 16 nodes
// (4 passes x 4 nodes, 16 lanes/node, 8 bf16 ch/lane, uint4 gathers) and writes
// h_act to LDS (XOR-swizzled 16B granules -> <=2-way bank aliasing, free).
// Phase B: the same wave MFMAs its 16 rows from LDS (no global h_act at all).

__global__ __launch_bounds__(256) void l1agg_l2t(
        const unsigned short* __restrict__ h1b, const float* __restrict__ a_src,
        const float* __restrict__ a_dst, const int* __restrict__ row_start,
        const int* __restrict__ csr_src, const float* __restrict__ b1,
        const unsigned short* __restrict__ w2t, const unsigned short* __restrict__ p2t,
        unsigned short* __restrict__ h2b, float* __restrict__ a_src2,
        float* __restrict__ a_dst2) {
    __shared__ unsigned short ha[64][128];   // 16 KB, swizzled granules
    int t = threadIdx.x;
    int w = t >> 6;
    uint32 lane = t & 63;
    uint32 quarter = lane >> 4;
    uint32 lane16 = lane & 15;
    int n0blk = blockIdx.x * 64;

    // ---------- phase A: aggregate 64 nodes into LDS ----------
    {
        uint32 c0 = lane16 * 8u;     // 8 channels per lane
        uint32 h = lane16 >> 1;      // head = c0 >> 4
        #pragma unroll
        for (int pass = 0; pass < 4; ++pass) {
            int n_local = w * 16 + pass * 4 + (int)quarter;
            int n = n0blk + n_local;
            int nc = (n < N_NODES) ? n : (N_NODES - 1);
            int beg = row_start[nc], end = row_start[nc + 1];
            int cnt = end - beg;
            int kmax = cnt;
            kmax = max(kmax, __shfl_xor(kmax, 16, 64));
            kmax = max(kmax, __shfl_xor(kmax, 32, 64));
            float adst = a_dst[nc * HEADS + h];
            float l = 0.f;
            float a0 = 0.f, a1 = 0.f, a2 = 0.f, a3 = 0.f;
            float a4 = 0.f, a5 = 0.f, a6 = 0.f, a7 = 0.f;

            for (int k = 0; k < kmax; k += 4) {
                uint32 ss[4]; float ee[4]; uint4 uu[4];
                #pragma unroll
                for (int q = 0; q < 4; ++q) {
                    int j = beg + k + q;
                    int jc = (j < end) ? j : (end - 1);    // cnt >= 1 (self loop)
                    ss[q] = (uint32)csr_src[jc];
                }
                #pragma unroll
                for (int q = 0; q < 4; ++q) ee[q] = a_src[ss[q] * 8u + h];
                #pragma unroll
                for (int q = 0; q < 4; ++q) uu[q] = *(const uint4*)&h1b[(ss[q] << 7) + c0];
                #pragma unroll
                for (int q = 0; q < 4; ++q) {
                    float e = ee[q] + adst;
                    e = fmaxf(e, NEG_SLOPE * e);          // leaky relu (log2 domain)
                    e = (k + q < cnt) ? e : -10000.f;     // masked lane -> p = 0
                    float p = exp2f(e);
                    l += p;
                    a0 = fmaf(p, __uint_as_float(uu[q].x << 16), a0);
                    a1 = fmaf(p, __uint_as_float(uu[q].x & 0xFFFF0000u), a1);
                    a2 = fmaf(p, __uint_as_float(uu[q].y << 16), a2);
                    a3 = fmaf(p, __uint_as_float(uu[q].y & 0xFFFF0000u), a3);
                    a4 = fmaf(p, __uint_as_float(uu[q].z << 16), a4);
                    a5 = fmaf(p, __uint_as_float(uu[q].z & 0xFFFF0000u), a5);
                    a6 = fmaf(p, __uint_as_float(uu[q].w << 16), a6);
                    a7 = fmaf(p, __uint_as_float(uu[q].w & 0xFFFF0000u), a7);
                }
            }

            float inv = 1.f / (l + 1e-16f);
            float v0 = a0 * inv + b1[c0 + 0];
            float v1 = a1 * inv + b1[c0 + 1];
            float v2 = a2 * inv + b1[c0 + 2];
            float v3 = a3 * inv + b1[c0 + 3];
            float v4 = a4 * inv + b1[c0 + 4];
            float v5 = a5 * inv + b1[c0 + 5];
            float v6 = a6 * inv + b1[c0 + 6];
            float v7 = a7 * inv + b1[c0 + 7];
            v0 = v0 > 0.f ? v0 : (__expf(v0) - 1.f);   // ELU
            v1 = v1 > 0.f ? v1 : (__expf(v1) - 1.f);
            v2 = v2 > 0.f ? v2 : (__expf(v2) - 1.f);
            v3 = v3 > 0.f ? v3 : (__expf(v3) - 1.f);
            v4 = v4 > 0.f ? v4 : (__expf(v4) - 1.f);
            v5 = v5 > 0.f ? v5 : (__expf(v5) - 1.f);
            v6 = v6 > 0.f ? v6 : (__expf(v6) - 1.f);
            v7 = v7 > 0.f ? v7 : (__expf(v7) - 1.f);
            uint4 packed;
            packed.x = (uint32)f2bf(v0) | ((uint32)f2bf(v1) << 16);
            packed.y = (uint32)f2bf(v2) | ((uint32)f2bf(v3) << 16);
            packed.z = (uint32)f2bf(v4) | ((uint32)f2bf(v5) << 16);
            packed.w = (uint32)f2bf(v6) | ((uint32)f2bf(v7) << 16);
            uint32 g = lane16 ^ ((uint32)n_local & 15u);   // swizzled granule
            *(uint4*)&ha[n_local][g * 8] = packed;
        }
    }
    __syncthreads();

    // ---------- phase B: layer-2 transform from LDS ----------
    {
        int l15 = (int)lane16, quad = (int)quarter;
        int n0 = n0blk + w * 16;
        int nloc = w * 16 + l15;

        bf16x8 af[4];
        #pragma unroll
        for (int s = 0; s < 4; ++s) {
            uint32 g = (uint32)(s * 4 + quad) ^ (uint32)l15;
            af[s] = *(const bf16x8*)&ha[nloc][g * 8];
        }

        #pragma unroll
        for (int tt = 0; tt < 5; ++tt) {
            const unsigned short* Brow = (tt < 4) ? &w2t[(tt * 16 + l15) * HID]
                                                  : &p2t[l15 * HID];
            f32x4 acc = {0.f, 0.f, 0.f, 0.f};
            #pragma unroll
            for (int s = 0; s < 4; ++s) {
                bf16x8 bf = *(const bf16x8*)&Brow[s * 32 + quad * 8];
                acc = __builtin_amdgcn_mfma_f32_16x16x32_bf16(af[s], bf, acc, 0, 0, 0);
            }
            int nodeb = n0 + quad * 4;
            if (tt < 4) {
                int ch = tt * 16 + l15;
                #pragma unroll
                for (int r = 0; r < 4; ++r)
                    if (nodeb + r < N_NODES)
                        h2b[(size_t)(nodeb + r) * OUT_DIM + ch] = f2bf(acc[r]);
            } else {
                #pragma unroll
                for (int r = 0; r < 4; ++r) {
                    if (nodeb + r < N_NODES) {
                        if (l15 == 0) a_src2[nodeb + r] = acc[r];
                        else if (l15 == 1) a_dst2[nodeb + r] = acc[r];
                    }
                }
            }
        }
    }
}

// ---------------- Layer 2: aggregate + log_softmax ----------------
// 4 nodes per wave: 16 lanes per node, 4 channels/lane (uint2 gathers).

__global__ __launch_bounds__(128) void l2_aggregate(
        const unsigned short* __restrict__ h2b, const float* __restrict__ a_src2,
        const float* __restrict__ a_dst2, const int* __restrict__ row_start,
        const int* __restrict__ csr_src, const float* __restrict__ b2,
        float* __restrict__ out) {
    int t = threadIdx.x;
    int w = t >> 6;
    uint32 lane = t & 63;
    uint32 quarter = lane >> 4;
    uint32 lane16 = lane & 15;
    int n = blockIdx.x * 8 + w * 4 + (int)quarter;
    uint32 c0 = lane16 * 4u;
    int beg = row_start[n], end = row_start[n + 1];
    int cnt = end - beg;
    int kmax = cnt;
    kmax = max(kmax, __shfl_xor(kmax, 16, 64));
    kmax = max(kmax, __shfl_xor(kmax, 32, 64));
    float adst = a_dst2[n];
    float l = 0.f, a0 = 0.f, a1 = 0.f, a2 = 0.f, a3 = 0.f;

    for (int k = 0; k < kmax; k += 4) {
        uint32 ss[4]; float ee[4]; uint2 uu[4];
        #pragma unroll
        for (int q = 0; q < 4; ++q) {
            int j = beg + k + q;
            int jc = (j < end) ? j : (end - 1);
            ss[q] = (uint32)csr_src[jc];
        }
        #pragma unroll
        for (int q = 0; q < 4; ++q) ee[q] = a_src2[ss[q]];
        #pragma unroll
        for (int q = 0; q < 4; ++q) uu[q] = *(const uint2*)&h2b[(ss[q] << 6) + c0];
        #pragma unroll
        for (int q = 0; q < 4; ++q) {
            float e = ee[q] + adst;
            e = fmaxf(e, NEG_SLOPE * e);
            e = (k + q < cnt) ? e : -10000.f;   // masked lane -> p = 0
            float p = exp2f(e);
            l += p;
            a0 = fmaf(p, __uint_as_float(uu[q].x << 16), a0);
            a1 = fmaf(p, __uint_as_float(uu[q].x & 0xFFFF0000u), a1);
            a2 = fmaf(p, __uint_as_float(uu[q].y << 16), a2);
            a3 = fmaf(p, __uint_as_float(uu[q].y & 0xFFFF0000u), a3);
        }
    }

    float inv = 1.f / (l + 1e-16f);
    float o0 = a0 * inv + b2[c0 + 0];
    float o1 = a1 * inv + b2[c0 + 1];
    float o2 = a2 * inv + b2[c0 + 2];
    float o3 = a3 * inv + b2[c0 + 3];
    // log_softmax over 64 channels = 16 lanes x 4 (quarter-wave reduction)
    float mx = fmaxf(fmaxf(o0, o1), fmaxf(o2, o3));
    #pragma unroll
    for (int m = 8; m > 0; m >>= 1) mx = fmaxf(mx, __shfl_xor(mx, m, 16));
    float ex = __expf(o0 - mx) + __expf(o1 - mx) + __expf(o2 - mx) + __expf(o3 - mx);
    #pragma unroll
    for (int m = 8; m > 0; m >>= 1) ex += __shfl_xor(ex, m, 16);
    float lse = mx + __logf(ex);
    float4 o = make_float4(o0 - lse, o1 - lse, o2 - lse, o3 - lse);
    *(float4*)&out[(size_t)n * OUT_DIM + c0] = o;
}

// ---------------- launch ----------------

extern "C" void kernel_launch(void* const* d_in, const int* in_sizes, int n_in,
                              void* d_out, int out_size, void* d_ws, size_t ws_size,
                              hipStream_t stream) {
    const float* x   = (const float*)d_in[0];
    const int*   ei  = (const int*)d_in[1];
    const float* W1  = (const float*)d_in[2];
    const float* as1 = (const float*)d_in[3];
    const float* ad1 = (const float*)d_in[4];
    const float* b1  = (const float*)d_in[5];
    const float* W2  = (const float*)d_in[6];
    const float* as2 = (const float*)d_in[7];
    const float* ad2 = (const float*)d_in[8];
    const float* b2  = (const float*)d_in[9];
    float* out = (float*)d_out;

    const int* src = ei;             // row 0
    const int* dst = ei + E_EDGES;   // row 1

    char* ws = (char*)d_ws;
    size_t off = 0;
    auto alloc = [&](size_t bytes) -> void* {
        void* p = ws + off;
        off += (bytes + 255) & ~size_t(255);
        return p;
    };
    unsigned short* xb     = (unsigned short*)alloc((size_t)N_NODES * IN_DIM * 2);
    unsigned short* h1b    = (unsigned short*)alloc((size_t)N_NODES * HID * 2);
    unsigned short* h2b    = (unsigned short*)alloc((size_t)N_NODES * OUT_DIM * 2);
    unsigned short* w1t    = (unsigned short*)alloc((size_t)HID * IN_DIM * 2);
    unsigned short* p1t    = (unsigned short*)alloc((size_t)16 * IN_DIM * 2);
    unsigned short* w2t    = (unsigned short*)alloc((size_t)OUT_DIM * HID * 2);
    unsigned short* p2t    = (unsigned short*)alloc((size_t)16 * HID * 2);
    float* a_src1    = (float*)alloc((size_t)N_NODES * HEADS * 4);
    float* a_dst1    = (float*)alloc((size_t)N_NODES * HEADS * 4);
    float* a_src2    = (float*)alloc((size_t)N_NODES * 4);
    float* a_dst2    = (float*)alloc((size_t)N_NODES * 4);
    int*   row_start = (int*)alloc((size_t)(N_NODES + 1) * 4);
    int*   csr_src   = (int*)alloc((size_t)ET * 4);
    uint32* pairs    = (uint32*)alloc((size_t)ET * 4);
    int*   cnt       = (int*)alloc((size_t)NB * NT * 4);
    int*   bucketStart = (int*)alloc((size_t)(NB + 1) * 4);

    prep_all<<<MEGA_A, 256, 0, stream>>>(dst, cnt, x, xb, W1, as1, ad1,
                                         W2, as2, ad2, w1t, p1t, w2t, p2t);
    bucket_scatter<<<NT, 256, 0, stream>>>(src, dst, cnt, bucketStart, pairs);
    build_l1t<<<MEGA_B, 256, 0, stream>>>(pairs, bucketStart, row_start, csr_src,
                                          xb, w1t, p1t, h1b, a_src1, a_dst1);
    l1agg_l2t<<<L1T_BLOCKS, 256, 0, stream>>>(h1b, a_src1, a_dst1, row_start, csr_src,
                                              b1, w2t, p2t, h2b, a_src2, a_dst2);
    l2_aggregate<<<N_NODES / 8, 128, 0, stream>>>(h2b, a_src2, a_dst2, row_start, csr_src, b2, out);
}